// Round 1
// baseline (14475.038 us; speedup 1.0000x reference)
//
#include <hip/hip_runtime.h>
#include <hip/hip_bf16.h>
#include <math.h>

#define L_ 12
#define C_ 768
#define H_ 12
#define FF_ 3072
#define V_ 50257
#define T_ 512
#define B_ 4
#define D_ 64
#define M_ (B_*T_)   // 2048 rows

// ---------------- embedding ----------------
__global__ void embed_kernel(const int* __restrict__ idx, const float* __restrict__ wte,
                             const float* __restrict__ wpe, float* __restrict__ x, int total)
{
    int i = blockIdx.x * blockDim.x + threadIdx.x;
    if (i >= total) return;
    int c = i % C_;
    int row = i / C_;
    int t = row % T_;
    x[i] = wte[(size_t)idx[row] * C_ + c] + wpe[(size_t)t * C_ + c];
}

// ---------------- layernorm (row per block, C=768, 256 threads) ----------------
__global__ __launch_bounds__(256) void layernorm_kernel(
    const float* __restrict__ x, const float* __restrict__ w, const float* __restrict__ b,
    float* __restrict__ out)
{
    int row = blockIdx.x;
    int tid = threadIdx.x;
    const float* xr = x + (size_t)row * C_;
    float lx[3];
    float s = 0.f;
#pragma unroll
    for (int i = 0; i < 3; ++i) { lx[i] = xr[tid + i * 256]; s += lx[i]; }
    __shared__ float red[4];
    for (int off = 32; off > 0; off >>= 1) s += __shfl_down(s, off, 64);
    if ((tid & 63) == 0) red[tid >> 6] = s;
    __syncthreads();
    if (tid == 0) red[0] = red[0] + red[1] + red[2] + red[3];
    __syncthreads();
    float mean = red[0] * (1.f / (float)C_);
    __syncthreads();
    float v = 0.f;
#pragma unroll
    for (int i = 0; i < 3; ++i) { float d = lx[i] - mean; v += d * d; }
    for (int off = 32; off > 0; off >>= 1) v += __shfl_down(v, off, 64);
    if ((tid & 63) == 0) red[tid >> 6] = v;
    __syncthreads();
    if (tid == 0) red[0] = red[0] + red[1] + red[2] + red[3];
    __syncthreads();
    float rstd = rsqrtf(red[0] * (1.f / (float)C_) + 1e-5f);
#pragma unroll
    for (int i = 0; i < 3; ++i) {
        int c = tid + i * 256;
        out[(size_t)row * C_ + c] = (lx[i] - mean) * rstd * w[c] + b[c];
    }
}

// ---------------- generic GEMM: C = A[M,K] @ B[K,N] (+bias)(+gelu)(+resid) ----------------
// 64x64 tile, 256 threads (16x16), 4x4 micro-tile, K-step 16. M%64==0, K%16==0 guaranteed.
__global__ __launch_bounds__(256) void gemm_kernel(
    const float* __restrict__ A, const float* __restrict__ B,
    const float* __restrict__ bias, const float* __restrict__ resid,
    float* __restrict__ C, int M, int N, int K, int gelu)
{
    __shared__ float As[16][68];
    __shared__ float Bs[16][68];
    int tid = threadIdx.x;
    int tx = tid & 15, ty = tid >> 4;
    int n0 = blockIdx.x * 64, m0 = blockIdx.y * 64;
    float acc[4][4] = {};
    for (int k0 = 0; k0 < K; k0 += 16) {
#pragma unroll
        for (int it = 0; it < 4; ++it) {
            int lin = it * 256 + tid;
            int i = lin >> 4, kk = lin & 15;
            As[kk][i] = A[(size_t)(m0 + i) * K + k0 + kk];
        }
#pragma unroll
        for (int it = 0; it < 4; ++it) {
            int lin = it * 256 + tid;
            int kk = lin >> 6, j = lin & 63;
            int n = n0 + j;
            Bs[kk][j] = (n < N) ? B[(size_t)(k0 + kk) * N + n] : 0.f;
        }
        __syncthreads();
#pragma unroll
        for (int kk = 0; kk < 16; ++kk) {
            float a[4], bb[4];
#pragma unroll
            for (int r = 0; r < 4; ++r) a[r] = As[kk][ty * 4 + r];
#pragma unroll
            for (int r = 0; r < 4; ++r) bb[r] = Bs[kk][tx * 4 + r];
#pragma unroll
            for (int i = 0; i < 4; ++i)
#pragma unroll
                for (int j = 0; j < 4; ++j) acc[i][j] += a[i] * bb[j];
        }
        __syncthreads();
    }
#pragma unroll
    for (int i = 0; i < 4; ++i) {
        int m = m0 + ty * 4 + i;
#pragma unroll
        for (int j = 0; j < 4; ++j) {
            int n = n0 + tx * 4 + j;
            if (n < N) {
                float v = acc[i][j];
                if (bias) v += bias[n];
                if (gelu) {
                    float t = 0.7978845608028654f * (v + 0.044715f * v * v * v);
                    v = 0.5f * v * (1.f + tanhf(t));
                }
                if (resid) v += resid[(size_t)m * N + n];
                C[(size_t)m * N + n] = v;
            }
        }
    }
}

// ---------------- fused causal attention: one block per (b,h,q) ----------------
// qkv layout [B*T, 3C]; q at +0, k at +C, v at +2C within a row; head h slice h*D.
__global__ __launch_bounds__(256) void attn_kernel(
    const float* __restrict__ qkv, float* __restrict__ y)
{
    const int C3 = 3 * C_;
    int bid = blockIdx.x;
    int q = bid % T_;
    int bh = bid / T_;
    int h = bh % H_;
    int b = bh / H_;
    __shared__ float qv[D_];
    __shared__ float sc[T_];
    __shared__ float red[8];
    __shared__ float part[4][D_];
    int tid = threadIdx.x;
    const float* base = qkv + (size_t)(b * T_) * C3;
    if (tid < D_) qv[tid] = base[(size_t)q * C3 + h * D_ + tid];
    __syncthreads();
    for (int k = tid; k < T_; k += 256) {
        float s;
        if (k <= q) {
            const float* kp = base + (size_t)k * C3 + C_ + h * D_;
            s = 0.f;
#pragma unroll 8
            for (int d = 0; d < D_; ++d) s += qv[d] * kp[d];
            s *= 0.125f;
        } else s = -INFINITY;
        sc[k] = s;
    }
    __syncthreads();
    float m = -INFINITY;
    for (int k = tid; k < T_; k += 256) m = fmaxf(m, sc[k]);
    for (int off = 32; off > 0; off >>= 1) m = fmaxf(m, __shfl_down(m, off, 64));
    if ((tid & 63) == 0) red[tid >> 6] = m;
    __syncthreads();
    if (tid == 0) red[0] = fmaxf(fmaxf(red[0], red[1]), fmaxf(red[2], red[3]));
    __syncthreads();
    m = red[0];
    __syncthreads();
    float s = 0.f;
    for (int k = tid; k < T_; k += 256) { float e = expf(sc[k] - m); sc[k] = e; s += e; }
    for (int off = 32; off > 0; off >>= 1) s += __shfl_down(s, off, 64);
    if ((tid & 63) == 0) red[4 + (tid >> 6)] = s;
    __syncthreads();
    if (tid == 0) red[0] = 1.f / (red[4] + red[5] + red[6] + red[7]);
    __syncthreads();
    float inv = red[0];
    int d = tid & 63, chunk = tid >> 6;
    float accv = 0.f;
    int k0 = chunk * 128;
    const float* vbase = base + 2 * C_ + h * D_ + d;
    for (int k = k0; k < k0 + 128; ++k) accv += sc[k] * vbase[(size_t)k * C3];
    part[chunk][d] = accv;
    __syncthreads();
    if (tid < D_) {
        float o = (part[0][tid] + part[1][tid] + part[2][tid] + part[3][tid]) * inv;
        y[((size_t)(b * T_ + q)) * C_ + h * D_ + tid] = o;
    }
}

// ---------------- cross-entropy over logits rows ----------------
__global__ __launch_bounds__(256) void loss_kernel(const float* __restrict__ logits,
    const int* __restrict__ targets, float* __restrict__ acc)
{
    int row = blockIdx.x;
    const float* lp = logits + (size_t)row * V_;
    int tid = threadIdx.x;
    __shared__ float red[8];
    float m = -INFINITY;
    for (int j = tid; j < V_; j += 256) m = fmaxf(m, lp[j]);
    for (int off = 32; off > 0; off >>= 1) m = fmaxf(m, __shfl_down(m, off, 64));
    if ((tid & 63) == 0) red[tid >> 6] = m;
    __syncthreads();
    if (tid == 0) red[0] = fmaxf(fmaxf(red[0], red[1]), fmaxf(red[2], red[3]));
    __syncthreads();
    m = red[0];
    __syncthreads();
    float s = 0.f;
    for (int j = tid; j < V_; j += 256) s += expf(lp[j] - m);
    for (int off = 32; off > 0; off >>= 1) s += __shfl_down(s, off, 64);
    if ((tid & 63) == 0) red[4 + (tid >> 6)] = s;
    __syncthreads();
    if (tid == 0) {
        float sum = red[4] + red[5] + red[6] + red[7];
        int t = targets[row];
        if (t != -100) {
            float nll = -(lp[t] - m - logf(sum));
            atomicAdd(&acc[0], nll);
            atomicAdd(&acc[1], 1.f);
        }
    }
}

__global__ void finalize_loss(const float* __restrict__ acc, float* __restrict__ out)
{
    out[0] = acc[0] / fmaxf(acc[1], 1.f);
}

extern "C" void kernel_launch(void* const* d_in, const int* in_sizes, int n_in,
                              void* d_out, int out_size, void* d_ws, size_t ws_size,
                              hipStream_t stream)
{
    const int*   idx     = (const int*)d_in[0];
    const int*   targets = (const int*)d_in[1];
    const float* wte     = (const float*)d_in[2];
    const float* wpe     = (const float*)d_in[3];
    const float* ln1_w   = (const float*)d_in[4];
    const float* ln1_b   = (const float*)d_in[5];
    const float* attn_w  = (const float*)d_in[6];
    const float* attn_b  = (const float*)d_in[7];
    const float* attnp_w = (const float*)d_in[8];
    const float* attnp_b = (const float*)d_in[9];
    const float* ln2_w   = (const float*)d_in[10];
    const float* ln2_b   = (const float*)d_in[11];
    const float* fc_w    = (const float*)d_in[12];
    const float* fc_b    = (const float*)d_in[13];
    const float* fcp_w   = (const float*)d_in[14];
    const float* fcp_b   = (const float*)d_in[15];
    const float* lnf_w   = (const float*)d_in[16];
    const float* lnf_b   = (const float*)d_in[17];
    const float* lm_w    = (const float*)d_in[18];

    float* logits = (float*)d_out;                    // [M_, V_]
    float* loss   = logits + (size_t)M_ * V_;         // 1 float

    float* ws  = (float*)d_ws;
    float* x   = ws;                        // M_*C_
    float* h   = x   + (size_t)M_ * C_;     // M_*C_
    float* qkv = h   + (size_t)M_ * C_;     // M_*3C_
    float* y   = qkv + (size_t)M_ * 3 * C_; // M_*C_
    float* ff  = y   + (size_t)M_ * C_;     // M_*FF_
    float* acc = ff  + (size_t)M_ * FF_;    // 2 floats

    // embedding
    {
        int total = M_ * C_;
        embed_kernel<<<(total + 255) / 256, 256, 0, stream>>>(idx, wte, wpe, x, total);
    }

    for (int l = 0; l < L_; ++l) {
        const float* l1w = ln1_w + (size_t)l * C_;
        const float* l1b = ln1_b + (size_t)l * C_;
        const float* aw  = attn_w + (size_t)l * C_ * 3 * C_;
        const float* ab  = attn_b + (size_t)l * 3 * C_;
        const float* pw  = attnp_w + (size_t)l * C_ * C_;
        const float* pb  = attnp_b + (size_t)l * C_;
        const float* l2w = ln2_w + (size_t)l * C_;
        const float* l2b = ln2_b + (size_t)l * C_;
        const float* fw  = fc_w + (size_t)l * C_ * FF_;
        const float* fb  = fc_b + (size_t)l * FF_;
        const float* qw  = fcp_w + (size_t)l * FF_ * C_;
        const float* qb  = fcp_b + (size_t)l * C_;

        // ln1
        layernorm_kernel<<<M_, 256, 0, stream>>>(x, l1w, l1b, h);
        // qkv = h @ aw + ab
        {
            dim3 grid((3 * C_ + 63) / 64, M_ / 64);
            gemm_kernel<<<grid, 256, 0, stream>>>(h, aw, ab, nullptr, qkv, M_, 3 * C_, C_, 0);
        }
        // attention
        attn_kernel<<<B_ * H_ * T_, 256, 0, stream>>>(qkv, y);
        // x = x + y @ pw + pb
        {
            dim3 grid((C_ + 63) / 64, M_ / 64);
            gemm_kernel<<<grid, 256, 0, stream>>>(y, pw, pb, x, x, M_, C_, C_, 0);
        }
        // ln2
        layernorm_kernel<<<M_, 256, 0, stream>>>(x, l2w, l2b, h);
        // ff = gelu(h @ fw + fb)
        {
            dim3 grid((FF_ + 63) / 64, M_ / 64);
            gemm_kernel<<<grid, 256, 0, stream>>>(h, fw, fb, nullptr, ff, M_, FF_, C_, 1);
        }
        // x = x + ff @ qw + qb
        {
            dim3 grid((C_ + 63) / 64, M_ / 64);
            gemm_kernel<<<grid, 256, 0, stream>>>(ff, qw, qb, x, x, M_, C_, FF_, 0);
        }
    }

    // final layernorm
    layernorm_kernel<<<M_, 256, 0, stream>>>(x, lnf_w, lnf_b, h);
    // logits = h @ lm_w
    {
        dim3 grid((V_ + 63) / 64, M_ / 64);
        gemm_kernel<<<grid, 256, 0, stream>>>(h, lm_w, nullptr, nullptr, logits, M_, V_, C_, 0);
    }
    // loss
    hipMemsetAsync(acc, 0, 2 * sizeof(float), stream);
    loss_kernel<<<M_, 256, 0, stream>>>(logits, targets, acc);
    finalize_loss<<<1, 1, 0, stream>>>(acc, loss);
}

// Round 2
// 6154.639 us; speedup vs baseline: 2.3519x; 2.3519x over previous
//
#include <hip/hip_runtime.h>
#include <hip/hip_bf16.h>
#include <math.h>

#define L_ 12
#define C_ 768
#define H_ 12
#define FF_ 3072
#define V_ 50257
#define VP_ 50304   // V padded to multiple of 128
#define T_ 512
#define B_ 4
#define D_ 64
#define M_ (B_*T_)   // 2048 rows

typedef __attribute__((ext_vector_type(8))) short short8;
typedef __attribute__((ext_vector_type(4))) float f32x4;
typedef __attribute__((ext_vector_type(8))) unsigned short us8;

__device__ __forceinline__ float bf2f(unsigned short u) {
    return __uint_as_float(((unsigned)u) << 16);
}
__device__ __forceinline__ unsigned short f2bf(float f) {
    unsigned u = __float_as_uint(f);
    unsigned r = u + 0x7fff + ((u >> 16) & 1);   // RNE
    return (unsigned short)(r >> 16);
}

// ---------------- weight convert + transpose: W[K,N] fp32 -> WT[Npad,K] bf16 ----------------
__global__ __launch_bounds__(256) void transpose_bf16_kernel(
    const float* __restrict__ W, __hip_bfloat16* __restrict__ WT,
    int K, int N, int Npad)
{
    __shared__ float tile[64][65];
    const float* Wl = W + (size_t)blockIdx.z * K * N;
    __hip_bfloat16* WTl = WT + (size_t)blockIdx.z * Npad * K;
    int k0 = blockIdx.y * 64, n0 = blockIdx.x * 64;
    int tid = threadIdx.x;
    int tn = tid & 63, tk4 = tid >> 6;
#pragma unroll 4
    for (int i = 0; i < 16; ++i) {
        int k = tk4 * 16 + i;
        int n = n0 + tn;
        tile[k][tn] = (n < N) ? Wl[(size_t)(k0 + k) * N + n] : 0.f;
    }
    __syncthreads();
    int tk = tid & 63, tn4 = tid >> 6;
#pragma unroll 4
    for (int i = 0; i < 16; ++i) {
        int n = tn4 * 16 + i;
        unsigned short v = f2bf(tile[tk][n]);
        ((unsigned short*)WTl)[(size_t)(n0 + n) * K + k0 + tk] = v;
    }
}

// ---------------- embedding (fp32 residual stream) ----------------
__global__ void embed_kernel(const int* __restrict__ idx, const float* __restrict__ wte,
                             const float* __restrict__ wpe, float* __restrict__ x, int total)
{
    int i = blockIdx.x * blockDim.x + threadIdx.x;
    if (i >= total) return;
    int c = i % C_;
    int row = i / C_;
    int t = row % T_;
    x[i] = wte[(size_t)idx[row] * C_ + c] + wpe[(size_t)t * C_ + c];
}

// ---------------- layernorm: fp32 in, bf16 out ----------------
__global__ __launch_bounds__(256) void layernorm_kernel(
    const float* __restrict__ x, const float* __restrict__ w, const float* __restrict__ b,
    __hip_bfloat16* __restrict__ out)
{
    int row = blockIdx.x;
    int tid = threadIdx.x;
    const float* xr = x + (size_t)row * C_;
    float lx[3];
    float s = 0.f;
#pragma unroll
    for (int i = 0; i < 3; ++i) { lx[i] = xr[tid + i * 256]; s += lx[i]; }
    __shared__ float red[4];
    for (int off = 32; off > 0; off >>= 1) s += __shfl_down(s, off, 64);
    if ((tid & 63) == 0) red[tid >> 6] = s;
    __syncthreads();
    if (tid == 0) red[0] = red[0] + red[1] + red[2] + red[3];
    __syncthreads();
    float mean = red[0] * (1.f / (float)C_);
    __syncthreads();
    float v = 0.f;
#pragma unroll
    for (int i = 0; i < 3; ++i) { float d = lx[i] - mean; v += d * d; }
    for (int off = 32; off > 0; off >>= 1) v += __shfl_down(v, off, 64);
    if ((tid & 63) == 0) red[tid >> 6] = v;
    __syncthreads();
    if (tid == 0) red[0] = red[0] + red[1] + red[2] + red[3];
    __syncthreads();
    float rstd = rsqrtf(red[0] * (1.f / (float)C_) + 1e-5f);
#pragma unroll
    for (int i = 0; i < 3; ++i) {
        int c = tid + i * 256;
        ((unsigned short*)out)[(size_t)row * C_ + c] = f2bf((lx[i] - mean) * rstd * w[c] + b[c]);
    }
}

// ---------------- bf16 MFMA GEMM: C = A[M,K] @ Bt[N,K]^T (+bias)(+gelu)(+resid) ----------------
// 128x128 tile, BK=32, 256 threads = 4 waves (2x2), 4x4 fragments of 16x16x32 per wave.
template<int OUTBF, int GELU, int RESID>
__global__ __launch_bounds__(256) void mfma_gemm(
    const __hip_bfloat16* __restrict__ A,
    const __hip_bfloat16* __restrict__ Bt,
    const float* __restrict__ bias,
    const float* __restrict__ resid,
    void* __restrict__ Cout,
    int M, int N, int K)
{
    __shared__ __hip_bfloat16 As[128 * 32];
    __shared__ __hip_bfloat16 Bs[128 * 32];
    int tid = threadIdx.x;
    int m0 = blockIdx.y * 128, n0 = blockIdx.x * 128;
    int lane = tid & 63, w = tid >> 6;
    int wm = w >> 1, wn = w & 1;
    int lrow = lane & 15, lk = (lane >> 4) * 8;
    f32x4 acc[4][4] = {};

    const __hip_bfloat16* Ab = A + (size_t)m0 * K;
    const __hip_bfloat16* Bb = Bt + (size_t)n0 * K;

    for (int k0 = 0; k0 < K; k0 += 32) {
#pragma unroll
        for (int i = 0; i < 2; ++i) {
            int c = tid + i * 256;
            int row = c >> 2, kk = (c & 3) * 8;
            const __hip_bfloat16* ga = Ab + (size_t)row * K + k0 + kk;
            const __hip_bfloat16* gb = Bb + (size_t)row * K + k0 + kk;
            __builtin_amdgcn_global_load_lds(
                (const __attribute__((address_space(1))) void*)ga,
                (__attribute__((address_space(3))) void*)(&As[c * 8]), 16, 0, 0);
            __builtin_amdgcn_global_load_lds(
                (const __attribute__((address_space(1))) void*)gb,
                (__attribute__((address_space(3))) void*)(&Bs[c * 8]), 16, 0, 0);
        }
        __syncthreads();
        short8 a[4], b[4];
#pragma unroll
        for (int i = 0; i < 4; ++i)
            a[i] = *(const short8*)&As[(wm * 64 + i * 16 + lrow) * 32 + lk];
#pragma unroll
        for (int j = 0; j < 4; ++j)
            b[j] = *(const short8*)&Bs[(wn * 64 + j * 16 + lrow) * 32 + lk];
#pragma unroll
        for (int i = 0; i < 4; ++i)
#pragma unroll
            for (int j = 0; j < 4; ++j)
                acc[i][j] = __builtin_amdgcn_mfma_f32_16x16x32_bf16(a[i], b[j], acc[i][j], 0, 0, 0);
        __syncthreads();
    }
    int r0 = (lane >> 4) * 4;
#pragma unroll
    for (int i = 0; i < 4; ++i) {
#pragma unroll
        for (int j = 0; j < 4; ++j) {
            int col = n0 + wn * 64 + j * 16 + lrow;
            if (col >= N) continue;
            float bv = bias ? bias[col] : 0.f;
#pragma unroll
            for (int r = 0; r < 4; ++r) {
                int row = m0 + wm * 64 + i * 16 + r0 + r;
                float v = acc[i][j][r] + bv;
                if (GELU) {
                    float t = 0.7978845608028654f * (v + 0.044715f * v * v * v);
                    v = 0.5f * v * (1.f + tanhf(t));
                }
                if (RESID) v += resid[(size_t)row * N + col];
                if (OUTBF)
                    ((unsigned short*)Cout)[(size_t)row * N + col] = f2bf(v);
                else
                    ((float*)Cout)[(size_t)row * N + col] = v;
            }
        }
    }
}

// ---------------- fused causal attention: one block per (b,h,q), bf16 qkv ----------------
__global__ __launch_bounds__(256) void attn_kernel(
    const __hip_bfloat16* __restrict__ qkv, __hip_bfloat16* __restrict__ y)
{
    const int C3 = 3 * C_;
    int bid = blockIdx.x;
    int q = bid % T_;
    int bh = bid / T_;
    int h = bh % H_;
    int b = bh / H_;
    __shared__ float qv[D_];
    __shared__ float sc[T_];
    __shared__ float red[8];
    __shared__ float part[4][D_];
    int tid = threadIdx.x;
    const __hip_bfloat16* base = qkv + (size_t)(b * T_) * C3;
    if (tid < D_)
        qv[tid] = bf2f(((const unsigned short*)base)[(size_t)q * C3 + h * D_ + tid]);
    __syncthreads();
    for (int k = tid; k < T_; k += 256) {
        float s;
        if (k <= q) {
            const us8* kp = (const us8*)(base + (size_t)k * C3 + C_ + h * D_);
            s = 0.f;
#pragma unroll
            for (int v8 = 0; v8 < 8; ++v8) {
                us8 kv = kp[v8];
#pragma unroll
                for (int e = 0; e < 8; ++e) s += qv[v8 * 8 + e] * bf2f(kv[e]);
            }
            s *= 0.125f;
        } else s = -INFINITY;
        sc[k] = s;
    }
    __syncthreads();
    float m = -INFINITY;
    for (int k = tid; k < T_; k += 256) m = fmaxf(m, sc[k]);
    for (int off = 32; off > 0; off >>= 1) m = fmaxf(m, __shfl_down(m, off, 64));
    if ((tid & 63) == 0) red[tid >> 6] = m;
    __syncthreads();
    if (tid == 0) red[0] = fmaxf(fmaxf(red[0], red[1]), fmaxf(red[2], red[3]));
    __syncthreads();
    m = red[0];
    __syncthreads();
    float s = 0.f;
    for (int k = tid; k < T_; k += 256) { float e = expf(sc[k] - m); sc[k] = e; s += e; }
    for (int off = 32; off > 0; off >>= 1) s += __shfl_down(s, off, 64);
    if ((tid & 63) == 0) red[4 + (tid >> 6)] = s;
    __syncthreads();
    if (tid == 0) red[0] = 1.f / (red[4] + red[5] + red[6] + red[7]);
    __syncthreads();
    float inv = red[0];
    int d = tid & 63, chunk = tid >> 6;
    float accv = 0.f;
    const unsigned short* vbase = (const unsigned short*)(base + 2 * C_ + h * D_) + d;
    for (int k = chunk * 128; k < chunk * 128 + 128; ++k)
        accv += sc[k] * bf2f(vbase[(size_t)k * C3]);
    part[chunk][d] = accv;
    __syncthreads();
    if (tid < D_) {
        float o = (part[0][tid] + part[1][tid] + part[2][tid] + part[3][tid]) * inv;
        ((unsigned short*)y)[((size_t)(b * T_ + q)) * C_ + h * D_ + tid] = f2bf(o);
    }
}

// ---------------- cross-entropy over logits rows ----------------
__global__ __launch_bounds__(256) void loss_kernel(const float* __restrict__ logits,
    const int* __restrict__ targets, float* __restrict__ acc)
{
    int row = blockIdx.x;
    const float* lp = logits + (size_t)row * V_;
    int tid = threadIdx.x;
    __shared__ float red[8];
    float m = -INFINITY;
    for (int j = tid; j < V_; j += 256) m = fmaxf(m, lp[j]);
    for (int off = 32; off > 0; off >>= 1) m = fmaxf(m, __shfl_down(m, off, 64));
    if ((tid & 63) == 0) red[tid >> 6] = m;
    __syncthreads();
    if (tid == 0) red[0] = fmaxf(fmaxf(red[0], red[1]), fmaxf(red[2], red[3]));
    __syncthreads();
    m = red[0];
    __syncthreads();
    float s = 0.f;
    for (int j = tid; j < V_; j += 256) s += expf(lp[j] - m);
    for (int off = 32; off > 0; off >>= 1) s += __shfl_down(s, off, 64);
    if ((tid & 63) == 0) red[4 + (tid >> 6)] = s;
    __syncthreads();
    if (tid == 0) {
        float sum = red[4] + red[5] + red[6] + red[7];
        int t = targets[row];
        if (t != -100) {
            float nll = -(lp[t] - m - logf(sum));
            atomicAdd(&acc[0], nll);
            atomicAdd(&acc[1], 1.f);
        }
    }
}

__global__ void finalize_loss(const float* __restrict__ acc, float* __restrict__ out)
{
    out[0] = acc[0] / fmaxf(acc[1], 1.f);
}

extern "C" void kernel_launch(void* const* d_in, const int* in_sizes, int n_in,
                              void* d_out, int out_size, void* d_ws, size_t ws_size,
                              hipStream_t stream)
{
    const int*   idx     = (const int*)d_in[0];
    const int*   targets = (const int*)d_in[1];
    const float* wte     = (const float*)d_in[2];
    const float* wpe     = (const float*)d_in[3];
    const float* ln1_w   = (const float*)d_in[4];
    const float* ln1_b   = (const float*)d_in[5];
    const float* attn_w  = (const float*)d_in[6];
    const float* attn_b  = (const float*)d_in[7];
    const float* attnp_w = (const float*)d_in[8];
    const float* attnp_b = (const float*)d_in[9];
    const float* ln2_w   = (const float*)d_in[10];
    const float* ln2_b   = (const float*)d_in[11];
    const float* fc_w    = (const float*)d_in[12];
    const float* fc_b    = (const float*)d_in[13];
    const float* fcp_w   = (const float*)d_in[14];
    const float* fcp_b   = (const float*)d_in[15];
    const float* lnf_w   = (const float*)d_in[16];
    const float* lnf_b   = (const float*)d_in[17];
    const float* lm_w    = (const float*)d_in[18];

    float* logits = (float*)d_out;                    // [M_, V_]
    float* loss   = logits + (size_t)M_ * V_;         // 1 float

    // ---- workspace layout ----
    char* p = (char*)d_ws;
    __hip_bfloat16* aw_t = (__hip_bfloat16*)p; p += (size_t)L_ * 3 * C_ * C_ * 2;   // [L][3C][C]
    __hip_bfloat16* pw_t = (__hip_bfloat16*)p; p += (size_t)L_ * C_ * C_ * 2;       // [L][C][C]
    __hip_bfloat16* fw_t = (__hip_bfloat16*)p; p += (size_t)L_ * FF_ * C_ * 2;      // [L][FF][C]
    __hip_bfloat16* qw_t = (__hip_bfloat16*)p; p += (size_t)L_ * C_ * FF_ * 2;      // [L][C][FF]
    __hip_bfloat16* lm_t = (__hip_bfloat16*)p; p += (size_t)VP_ * C_ * 2;           // [VP][C]
    float*          x    = (float*)p;          p += (size_t)M_ * C_ * 4;
    __hip_bfloat16* h    = (__hip_bfloat16*)p; p += (size_t)M_ * C_ * 2;
    __hip_bfloat16* qkv  = (__hip_bfloat16*)p; p += (size_t)M_ * 3 * C_ * 2;
    __hip_bfloat16* y    = (__hip_bfloat16*)p; p += (size_t)M_ * C_ * 2;
    __hip_bfloat16* ff   = (__hip_bfloat16*)p; p += (size_t)M_ * FF_ * 2;
    float*          acc  = (float*)p;          p += 2 * 4;

    // ---- weight convert+transpose pre-pass ----
    transpose_bf16_kernel<<<dim3(3 * C_ / 64, C_ / 64, L_), 256, 0, stream>>>(attn_w, aw_t, C_, 3 * C_, 3 * C_);
    transpose_bf16_kernel<<<dim3(C_ / 64, C_ / 64, L_), 256, 0, stream>>>(attnp_w, pw_t, C_, C_, C_);
    transpose_bf16_kernel<<<dim3(FF_ / 64, C_ / 64, L_), 256, 0, stream>>>(fc_w, fw_t, C_, FF_, FF_);
    transpose_bf16_kernel<<<dim3(C_ / 64, FF_ / 64, L_), 256, 0, stream>>>(fcp_w, qw_t, FF_, C_, C_);
    transpose_bf16_kernel<<<dim3(VP_ / 64, C_ / 64, 1), 256, 0, stream>>>(lm_w, lm_t, C_, V_, VP_);

    // ---- embedding ----
    {
        int total = M_ * C_;
        embed_kernel<<<(total + 255) / 256, 256, 0, stream>>>(idx, wte, wpe, x, total);
    }

    for (int l = 0; l < L_; ++l) {
        const float* l1w = ln1_w + (size_t)l * C_;
        const float* l1b = ln1_b + (size_t)l * C_;
        const __hip_bfloat16* aw = aw_t + (size_t)l * 3 * C_ * C_;
        const float* ab  = attn_b + (size_t)l * 3 * C_;
        const __hip_bfloat16* pw = pw_t + (size_t)l * C_ * C_;
        const float* pb  = attnp_b + (size_t)l * C_;
        const float* l2w = ln2_w + (size_t)l * C_;
        const float* l2b = ln2_b + (size_t)l * C_;
        const __hip_bfloat16* fw = fw_t + (size_t)l * FF_ * C_;
        const float* fb  = fc_b + (size_t)l * FF_;
        const __hip_bfloat16* qw = qw_t + (size_t)l * C_ * FF_;
        const float* qb  = fcp_b + (size_t)l * C_;

        layernorm_kernel<<<M_, 256, 0, stream>>>(x, l1w, l1b, h);
        mfma_gemm<1, 0, 0><<<dim3(3 * C_ / 128, M_ / 128), 256, 0, stream>>>(
            h, aw, ab, nullptr, qkv, M_, 3 * C_, C_);
        attn_kernel<<<B_ * H_ * T_, 256, 0, stream>>>(qkv, y);
        mfma_gemm<0, 0, 1><<<dim3(C_ / 128, M_ / 128), 256, 0, stream>>>(
            y, pw, pb, x, x, M_, C_, C_);
        layernorm_kernel<<<M_, 256, 0, stream>>>(x, l2w, l2b, h);
        mfma_gemm<1, 1, 0><<<dim3(FF_ / 128, M_ / 128), 256, 0, stream>>>(
            h, fw, fb, nullptr, ff, M_, FF_, C_);
        mfma_gemm<0, 0, 1><<<dim3(C_ / 128, M_ / 128), 256, 0, stream>>>(
            ff, qw, qb, x, x, M_, C_, FF_);
    }

    layernorm_kernel<<<M_, 256, 0, stream>>>(x, lnf_w, lnf_b, h);
    mfma_gemm<0, 0, 0><<<dim3(VP_ / 128, M_ / 128), 256, 0, stream>>>(
        h, lm_t, nullptr, nullptr, logits, M_, V_, C_);

    hipMemsetAsync(acc, 0, 2 * sizeof(float), stream);
    loss_kernel<<<M_, 256, 0, stream>>>(logits, targets, acc);
    finalize_loss<<<1, 1, 0, stream>>>(acc, loss);
}

// Round 3
// 3309.121 us; speedup vs baseline: 4.3743x; 1.8599x over previous
//
#include <hip/hip_runtime.h>
#include <hip/hip_bf16.h>
#include <math.h>

#define L_ 12
#define C_ 768
#define H_ 12
#define FF_ 3072
#define V_ 50257
#define VP_ 50304   // V padded to multiple of 128
#define T_ 512
#define B_ 4
#define D_ 64
#define M_ (B_*T_)   // 2048 rows
#define BH_ (B_*H_)  // 48

typedef __attribute__((ext_vector_type(8))) short short8;
typedef __attribute__((ext_vector_type(4))) float f32x4;
typedef __attribute__((ext_vector_type(8))) unsigned short us8;

__device__ __forceinline__ float bf2f(unsigned short u) {
    return __uint_as_float(((unsigned)u) << 16);
}
__device__ __forceinline__ unsigned short f2bf(float f) {
    unsigned u = __float_as_uint(f);
    unsigned r = u + 0x7fff + ((u >> 16) & 1);   // RNE
    return (unsigned short)(r >> 16);
}

// ---------------- weight convert + transpose: W[K,N] fp32 -> WT[Npad,K] bf16 ----------------
__global__ __launch_bounds__(256) void transpose_bf16_kernel(
    const float* __restrict__ W, __hip_bfloat16* __restrict__ WT,
    int K, int N, int Npad)
{
    __shared__ float tile[64][65];
    const float* Wl = W + (size_t)blockIdx.z * K * N;
    __hip_bfloat16* WTl = WT + (size_t)blockIdx.z * Npad * K;
    int k0 = blockIdx.y * 64, n0 = blockIdx.x * 64;
    int tid = threadIdx.x;
    int tn = tid & 63, tk4 = tid >> 6;
#pragma unroll 4
    for (int i = 0; i < 16; ++i) {
        int k = tk4 * 16 + i;
        int n = n0 + tn;
        tile[k][tn] = (n < N) ? Wl[(size_t)(k0 + k) * N + n] : 0.f;
    }
    __syncthreads();
    int tk = tid & 63, tn4 = tid >> 6;
#pragma unroll 4
    for (int i = 0; i < 16; ++i) {
        int n = tn4 * 16 + i;
        unsigned short v = f2bf(tile[tk][n]);
        ((unsigned short*)WTl)[(size_t)(n0 + n) * K + k0 + tk] = v;
    }
}

// ---------------- embedding (fp32 residual stream) ----------------
__global__ void embed_kernel(const int* __restrict__ idx, const float* __restrict__ wte,
                             const float* __restrict__ wpe, float* __restrict__ x, int total)
{
    int i = blockIdx.x * blockDim.x + threadIdx.x;
    if (i >= total) return;
    int c = i % C_;
    int row = i / C_;
    int t = row % T_;
    x[i] = wte[(size_t)idx[row] * C_ + c] + wpe[(size_t)t * C_ + c];
}

// ---------------- layernorm: fp32 in, bf16 out ----------------
__global__ __launch_bounds__(256) void layernorm_kernel(
    const float* __restrict__ x, const float* __restrict__ w, const float* __restrict__ b,
    __hip_bfloat16* __restrict__ out)
{
    int row = blockIdx.x;
    int tid = threadIdx.x;
    const float* xr = x + (size_t)row * C_;
    float lx[3];
    float s = 0.f;
#pragma unroll
    for (int i = 0; i < 3; ++i) { lx[i] = xr[tid + i * 256]; s += lx[i]; }
    __shared__ float red[4];
    for (int off = 32; off > 0; off >>= 1) s += __shfl_down(s, off, 64);
    if ((tid & 63) == 0) red[tid >> 6] = s;
    __syncthreads();
    if (tid == 0) red[0] = red[0] + red[1] + red[2] + red[3];
    __syncthreads();
    float mean = red[0] * (1.f / (float)C_);
    __syncthreads();
    float v = 0.f;
#pragma unroll
    for (int i = 0; i < 3; ++i) { float d = lx[i] - mean; v += d * d; }
    for (int off = 32; off > 0; off >>= 1) v += __shfl_down(v, off, 64);
    if ((tid & 63) == 0) red[tid >> 6] = v;
    __syncthreads();
    if (tid == 0) red[0] = red[0] + red[1] + red[2] + red[3];
    __syncthreads();
    float rstd = rsqrtf(red[0] * (1.f / (float)C_) + 1e-5f);
#pragma unroll
    for (int i = 0; i < 3; ++i) {
        int c = tid + i * 256;
        ((unsigned short*)out)[(size_t)row * C_ + c] = f2bf((lx[i] - mean) * rstd * w[c] + b[c]);
    }
}

// ---------------- bf16 MFMA GEMM: C = A[M,K] @ Bt[N,K]^T (+bias)(+gelu)(+resid) ----------------
// 128x128 tile, BK=32, 256 threads = 4 waves (2x2). XCD-panel-grouped block order:
// xcd = bid&7 owns N-panels [xcd*ppx, (xcd+1)*ppx), M iterates fastest (16 M-panels).
template<int OUTBF, int GELU, int RESID>
__global__ __launch_bounds__(256) void mfma_gemm(
    const __hip_bfloat16* __restrict__ A,
    const __hip_bfloat16* __restrict__ Bt,
    const float* __restrict__ bias,
    const float* __restrict__ resid,
    void* __restrict__ Cout,
    int M, int N, int K, int NB)
{
    int ppx = (NB + 7) >> 3;
    int xcd = blockIdx.x & 7;
    int sidx = blockIdx.x >> 3;
    int npan = xcd * ppx + (sidx >> 4);
    int mpan = sidx & 15;
    if (npan >= NB) return;
    int m0 = mpan * 128, n0 = npan * 128;

    __shared__ __hip_bfloat16 As[128 * 32];
    __shared__ __hip_bfloat16 Bs[128 * 32];
    int tid = threadIdx.x;
    int lane = tid & 63, w = tid >> 6;
    int wm = w >> 1, wn = w & 1;
    int lrow = lane & 15, lk = (lane >> 4) * 8;
    f32x4 acc[4][4] = {};

    const __hip_bfloat16* Ab = A + (size_t)m0 * K;
    const __hip_bfloat16* Bb = Bt + (size_t)n0 * K;

    for (int k0 = 0; k0 < K; k0 += 32) {
#pragma unroll
        for (int i = 0; i < 2; ++i) {
            int c = tid + i * 256;
            int row = c >> 2, kk = (c & 3) * 8;
            const __hip_bfloat16* ga = Ab + (size_t)row * K + k0 + kk;
            const __hip_bfloat16* gb = Bb + (size_t)row * K + k0 + kk;
            __builtin_amdgcn_global_load_lds(
                (const __attribute__((address_space(1))) void*)ga,
                (__attribute__((address_space(3))) void*)(&As[c * 8]), 16, 0, 0);
            __builtin_amdgcn_global_load_lds(
                (const __attribute__((address_space(1))) void*)gb,
                (__attribute__((address_space(3))) void*)(&Bs[c * 8]), 16, 0, 0);
        }
        __syncthreads();
        short8 a[4], b[4];
#pragma unroll
        for (int i = 0; i < 4; ++i)
            a[i] = *(const short8*)&As[(wm * 64 + i * 16 + lrow) * 32 + lk];
#pragma unroll
        for (int j = 0; j < 4; ++j)
            b[j] = *(const short8*)&Bs[(wn * 64 + j * 16 + lrow) * 32 + lk];
#pragma unroll
        for (int i = 0; i < 4; ++i)
#pragma unroll
            for (int j = 0; j < 4; ++j)
                acc[i][j] = __builtin_amdgcn_mfma_f32_16x16x32_bf16(a[i], b[j], acc[i][j], 0, 0, 0);
        __syncthreads();
    }
    int r0 = (lane >> 4) * 4;
#pragma unroll
    for (int i = 0; i < 4; ++i) {
#pragma unroll
        for (int j = 0; j < 4; ++j) {
            int col = n0 + wn * 64 + j * 16 + lrow;
            if (col >= N) continue;
            float bv = bias ? bias[col] : 0.f;
#pragma unroll
            for (int r = 0; r < 4; ++r) {
                int row = m0 + wm * 64 + i * 16 + r0 + r;
                float v = acc[i][j][r] + bv;
                if (GELU) {
                    float t = 0.7978845608028654f * (v + 0.044715f * v * v * v);
                    v = 0.5f * v * (1.f + tanhf(t));
                }
                if (RESID) v += resid[(size_t)row * N + col];
                if (OUTBF)
                    ((unsigned short*)Cout)[(size_t)row * N + col] = f2bf(v);
                else
                    ((float*)Cout)[(size_t)row * N + col] = v;
            }
        }
    }
}

// ---------------- qkv pack: Qp/Kp [BH][T][64], Vt [BH][64][T] ----------------
__global__ __launch_bounds__(256) void qkv_pack_kernel(
    const unsigned short* __restrict__ qkv,
    unsigned short* __restrict__ Qp, unsigned short* __restrict__ Kp,
    unsigned short* __restrict__ Vt)
{
    const int C3 = 3 * C_;
    int bx = blockIdx.x;
    int bh = bx >> 3;            // 0..47
    int t0 = (bx & 7) * 64;
    int b = bh / H_, h = bh % H_;
    const unsigned short* base = qkv + ((size_t)(b * T_ + t0)) * C3 + h * 64;
    int tid = threadIdx.x;
    __shared__ unsigned short vt_tile[64][72];
#pragma unroll
    for (int i = 0; i < 2; ++i) {
        int p = tid + i * 256;          // 0..511
        int row = p >> 3, cv = (p & 7) * 8;
        us8 q8 = *(const us8*)(base + (size_t)row * C3 + cv);
        *(us8*)(Qp + ((size_t)bh * T_ + t0 + row) * 64 + cv) = q8;
        us8 k8 = *(const us8*)(base + (size_t)row * C3 + C_ + cv);
        *(us8*)(Kp + ((size_t)bh * T_ + t0 + row) * 64 + cv) = k8;
        us8 v8 = *(const us8*)(base + (size_t)row * C3 + 2 * C_ + cv);
#pragma unroll
        for (int e = 0; e < 8; ++e) vt_tile[cv + e][row] = v8[e];
    }
    __syncthreads();
#pragma unroll
    for (int i = 0; i < 2; ++i) {
        int p = tid + i * 256;
        int d = p >> 3, tl = (p & 7) * 8;
        us8 o = *(const us8*)(&vt_tile[d][tl]);
        *(us8*)(Vt + ((size_t)bh * 64 + d) * T_ + t0 + tl) = o;
    }
}

// ---------------- MFMA flash attention: 1 wave per 16 q-rows ----------------
// grid = 8 xcd * 6 bh * 32 qtiles = 1536 blocks, 64 threads.
__global__ __launch_bounds__(64) void flash_attn_kernel(
    const unsigned short* __restrict__ Qp, const unsigned short* __restrict__ Kp,
    const unsigned short* __restrict__ Vt, unsigned short* __restrict__ y)
{
    int bid = blockIdx.x;
    int xcd = bid & 7;
    int s_ = bid >> 3;                 // 0..191
    int bh = xcd * 6 + (s_ % 6);       // 0..47, 6 heads per XCD
    int qi = s_ / 6;                   // 0..31
    int b = bh / H_, h = bh % H_;
    int q0 = qi * 16;
    int lane = threadIdx.x;
    int c = lane & 15, g = lane >> 4;

    const unsigned short* Qb = Qp + ((size_t)bh * T_ + q0) * 64;
    const unsigned short* Kb = Kp + (size_t)bh * T_ * 64;
    const unsigned short* Vb = Vt + (size_t)bh * 64 * T_;

    short8 qf0 = *(const short8*)(Qb + (size_t)c * 64 + g * 8);
    short8 qf1 = *(const short8*)(Qb + (size_t)c * 64 + 32 + g * 8);

    f32x4 o[4] = {};
    float mrow[4], lrow[4];
#pragma unroll
    for (int r = 0; r < 4; ++r) { mrow[r] = -1e30f; lrow[r] = 0.f; }

    __shared__ unsigned short P_lds[16 * 40];

    int kvend = q0 + 16;
    for (int kv0 = 0; kv0 < kvend; kv0 += 32) {
        f32x4 s[2] = {};
#pragma unroll
        for (int t = 0; t < 2; ++t) {
            const unsigned short* Kt = Kb + (size_t)(kv0 + t * 16 + c) * 64;
            short8 b0 = *(const short8*)(Kt + g * 8);
            short8 b1 = *(const short8*)(Kt + 32 + g * 8);
            s[t] = __builtin_amdgcn_mfma_f32_16x16x32_bf16(qf0, b0, s[t], 0, 0, 0);
            s[t] = __builtin_amdgcn_mfma_f32_16x16x32_bf16(qf1, b1, s[t], 0, 0, 0);
        }
        // scale + causal mask (acc: col=c=kv-local, row=g*4+r=q-local)
        if (kv0 + 32 > q0) {
#pragma unroll
            for (int t = 0; t < 2; ++t)
#pragma unroll
                for (int r = 0; r < 4; ++r) {
                    int kv = kv0 + t * 16 + c;
                    int qq = q0 + g * 4 + r;
                    float v = s[t][r] * 0.125f;
                    s[t][r] = (kv <= qq) ? v : -1e30f;
                }
        } else {
#pragma unroll
            for (int t = 0; t < 2; ++t)
#pragma unroll
                for (int r = 0; r < 4; ++r) s[t][r] *= 0.125f;
        }
        // online softmax, rows reduced across 16-lane groups
        float pmax[4];
#pragma unroll
        for (int r = 0; r < 4; ++r) pmax[r] = fmaxf(s[0][r], s[1][r]);
#pragma unroll
        for (int w = 1; w < 16; w <<= 1)
#pragma unroll
            for (int r = 0; r < 4; ++r) pmax[r] = fmaxf(pmax[r], __shfl_xor(pmax[r], w, 64));
        float scale[4], psum[4];
#pragma unroll
        for (int r = 0; r < 4; ++r) {
            float mnew = fmaxf(mrow[r], pmax[r]);
            scale[r] = __expf(mrow[r] - mnew);
            mrow[r] = mnew;
            s[0][r] = __expf(s[0][r] - mnew);
            s[1][r] = __expf(s[1][r] - mnew);
            psum[r] = s[0][r] + s[1][r];
        }
#pragma unroll
        for (int w = 1; w < 16; w <<= 1)
#pragma unroll
            for (int r = 0; r < 4; ++r) psum[r] += __shfl_xor(psum[r], w, 64);
#pragma unroll
        for (int r = 0; r < 4; ++r) lrow[r] = lrow[r] * scale[r] + psum[r];
#pragma unroll
        for (int j = 0; j < 4; ++j)
#pragma unroll
            for (int r = 0; r < 4; ++r) o[j][r] *= scale[r];
        // P -> LDS (bf16), rows 4g+r, cols t*16+c; row stride 40 to spread banks
#pragma unroll
        for (int t = 0; t < 2; ++t)
#pragma unroll
            for (int r = 0; r < 4; ++r)
                P_lds[(g * 4 + r) * 40 + t * 16 + c] = f2bf(s[t][r]);
        __syncthreads();
        // PV: A = P[16q x 32kv] from LDS, B = V^T fragments from Vt
        short8 pf = *(const short8*)&P_lds[c * 40 + g * 8];
#pragma unroll
        for (int j = 0; j < 4; ++j) {
            short8 vf = *(const short8*)(Vb + (size_t)(j * 16 + c) * T_ + kv0 + g * 8);
            o[j] = __builtin_amdgcn_mfma_f32_16x16x32_bf16(pf, vf, o[j], 0, 0, 0);
        }
        __syncthreads();
    }
    unsigned short* yb = y + ((size_t)(b * T_ + q0)) * C_ + h * 64;
#pragma unroll
    for (int r = 0; r < 4; ++r) {
        float inv = 1.f / lrow[r];
#pragma unroll
        for (int j = 0; j < 4; ++j)
            yb[(size_t)(g * 4 + r) * C_ + j * 16 + c] = f2bf(o[j][r] * inv);
    }
}

// ---------------- single-pass online cross-entropy ----------------
__global__ __launch_bounds__(256) void loss_kernel(const float* __restrict__ logits,
    const int* __restrict__ targets, float* __restrict__ acc)
{
    int row = blockIdx.x;
    const float* lp = logits + (size_t)row * V_;
    int tid = threadIdx.x;
    float m = -1e30f, s = 0.f;
    for (int j = tid; j < V_; j += 256) {
        float x = lp[j];
        float mn = fmaxf(m, x);
        s = s * __expf(m - mn) + __expf(x - mn);
        m = mn;
    }
    for (int off = 32; off > 0; off >>= 1) {
        float mo = __shfl_down(m, off, 64);
        float so = __shfl_down(s, off, 64);
        float mn = fmaxf(m, mo);
        s = s * __expf(m - mn) + so * __expf(mo - mn);
        m = mn;
    }
    __shared__ float rm[4], rs[4];
    if ((tid & 63) == 0) { rm[tid >> 6] = m; rs[tid >> 6] = s; }
    __syncthreads();
    if (tid == 0) {
        float M = rm[0], S = rs[0];
        for (int i = 1; i < 4; ++i) {
            float mn = fmaxf(M, rm[i]);
            S = S * __expf(M - mn) + rs[i] * __expf(rm[i] - mn);
            M = mn;
        }
        int t = targets[row];
        if (t != -100) {
            float nll = -(lp[t] - M - logf(S));
            atomicAdd(&acc[0], nll);
            atomicAdd(&acc[1], 1.f);
        }
    }
}

__global__ void finalize_loss(const float* __restrict__ acc, float* __restrict__ out)
{
    out[0] = acc[0] / fmaxf(acc[1], 1.f);
}

extern "C" void kernel_launch(void* const* d_in, const int* in_sizes, int n_in,
                              void* d_out, int out_size, void* d_ws, size_t ws_size,
                              hipStream_t stream)
{
    const int*   idx     = (const int*)d_in[0];
    const int*   targets = (const int*)d_in[1];
    const float* wte     = (const float*)d_in[2];
    const float* wpe     = (const float*)d_in[3];
    const float* ln1_w   = (const float*)d_in[4];
    const float* ln1_b   = (const float*)d_in[5];
    const float* attn_w  = (const float*)d_in[6];
    const float* attn_b  = (const float*)d_in[7];
    const float* attnp_w = (const float*)d_in[8];
    const float* attnp_b = (const float*)d_in[9];
    const float* ln2_w   = (const float*)d_in[10];
    const float* ln2_b   = (const float*)d_in[11];
    const float* fc_w    = (const float*)d_in[12];
    const float* fc_b    = (const float*)d_in[13];
    const float* fcp_w   = (const float*)d_in[14];
    const float* fcp_b   = (const float*)d_in[15];
    const float* lnf_w   = (const float*)d_in[16];
    const float* lnf_b   = (const float*)d_in[17];
    const float* lm_w    = (const float*)d_in[18];

    float* logits = (float*)d_out;                    // [M_, V_]
    float* loss   = logits + (size_t)M_ * V_;         // 1 float

    // ---- workspace layout ----
    char* p = (char*)d_ws;
    __hip_bfloat16* aw_t = (__hip_bfloat16*)p; p += (size_t)L_ * 3 * C_ * C_ * 2;
    __hip_bfloat16* pw_t = (__hip_bfloat16*)p; p += (size_t)L_ * C_ * C_ * 2;
    __hip_bfloat16* fw_t = (__hip_bfloat16*)p; p += (size_t)L_ * FF_ * C_ * 2;
    __hip_bfloat16* qw_t = (__hip_bfloat16*)p; p += (size_t)L_ * C_ * FF_ * 2;
    __hip_bfloat16* lm_t = (__hip_bfloat16*)p; p += (size_t)VP_ * C_ * 2;
    float*          x    = (float*)p;          p += (size_t)M_ * C_ * 4;
    __hip_bfloat16* h    = (__hip_bfloat16*)p; p += (size_t)M_ * C_ * 2;
    __hip_bfloat16* qkv  = (__hip_bfloat16*)p; p += (size_t)M_ * 3 * C_ * 2;
    __hip_bfloat16* y    = (__hip_bfloat16*)p; p += (size_t)M_ * C_ * 2;
    __hip_bfloat16* ff   = (__hip_bfloat16*)p; p += (size_t)M_ * FF_ * 2;
    unsigned short* Qp   = (unsigned short*)p; p += (size_t)BH_ * T_ * 64 * 2;
    unsigned short* Kp   = (unsigned short*)p; p += (size_t)BH_ * T_ * 64 * 2;
    unsigned short* Vt   = (unsigned short*)p; p += (size_t)BH_ * 64 * T_ * 2;
    float*          acc  = (float*)p;          p += 2 * 4;

    // ---- weight convert+transpose pre-pass ----
    transpose_bf16_kernel<<<dim3(3 * C_ / 64, C_ / 64, L_), 256, 0, stream>>>(attn_w, aw_t, C_, 3 * C_, 3 * C_);
    transpose_bf16_kernel<<<dim3(C_ / 64, C_ / 64, L_), 256, 0, stream>>>(attnp_w, pw_t, C_, C_, C_);
    transpose_bf16_kernel<<<dim3(FF_ / 64, C_ / 64, L_), 256, 0, stream>>>(fc_w, fw_t, C_, FF_, FF_);
    transpose_bf16_kernel<<<dim3(C_ / 64, FF_ / 64, L_), 256, 0, stream>>>(fcp_w, qw_t, FF_, C_, C_);
    transpose_bf16_kernel<<<dim3(VP_ / 64, C_ / 64, 1), 256, 0, stream>>>(lm_w, lm_t, C_, V_, VP_);

    // ---- embedding ----
    {
        int total = M_ * C_;
        embed_kernel<<<(total + 255) / 256, 256, 0, stream>>>(idx, wte, wpe, x, total);
    }

    // grid size helper: 8 XCDs * ceil(NB/8) panels * 16 M-panels
    #define GEMM_GRID(NB) (8 * (((NB) + 7) / 8) * 16)

    for (int l = 0; l < L_; ++l) {
        const float* l1w = ln1_w + (size_t)l * C_;
        const float* l1b = ln1_b + (size_t)l * C_;
        const __hip_bfloat16* aw = aw_t + (size_t)l * 3 * C_ * C_;
        const float* ab  = attn_b + (size_t)l * 3 * C_;
        const __hip_bfloat16* pw = pw_t + (size_t)l * C_ * C_;
        const float* pb  = attnp_b + (size_t)l * C_;
        const float* l2w = ln2_w + (size_t)l * C_;
        const float* l2b = ln2_b + (size_t)l * C_;
        const __hip_bfloat16* fw = fw_t + (size_t)l * FF_ * C_;
        const float* fb  = fc_b + (size_t)l * FF_;
        const __hip_bfloat16* qw = qw_t + (size_t)l * C_ * FF_;
        const float* qb  = fcp_b + (size_t)l * C_;

        layernorm_kernel<<<M_, 256, 0, stream>>>(x, l1w, l1b, h);
        mfma_gemm<1, 0, 0><<<GEMM_GRID(18), 256, 0, stream>>>(
            h, aw, ab, nullptr, qkv, M_, 3 * C_, C_, 18);
        qkv_pack_kernel<<<BH_ * 8, 256, 0, stream>>>((const unsigned short*)qkv, Qp, Kp, Vt);
        flash_attn_kernel<<<8 * 6 * 32, 64, 0, stream>>>(Qp, Kp, Vt, (unsigned short*)y);
        mfma_gemm<0, 0, 1><<<GEMM_GRID(6), 256, 0, stream>>>(
            y, pw, pb, x, x, M_, C_, C_, 6);
        layernorm_kernel<<<M_, 256, 0, stream>>>(x, l2w, l2b, h);
        mfma_gemm<1, 1, 0><<<GEMM_GRID(24), 256, 0, stream>>>(
            h, fw, fb, nullptr, ff, M_, FF_, C_, 24);
        mfma_gemm<0, 0, 1><<<GEMM_GRID(6), 256, 0, stream>>>(
            ff, qw, qb, x, x, M_, C_, FF_, 6);
    }

    layernorm_kernel<<<M_, 256, 0, stream>>>(x, lnf_w, lnf_b, h);
    mfma_gemm<0, 0, 0><<<GEMM_GRID(393), 256, 0, stream>>>(
        h, lm_t, nullptr, nullptr, logits, M_, V_, C_, 393);

    hipMemsetAsync(acc, 0, 2 * sizeof(float), stream);
    loss_kernel<<<M_, 256, 0, stream>>>(logits, targets, acc);
    finalize_loss<<<1, 1, 0, stream>>>(acc, loss);
}

// Round 4
// 3243.200 us; speedup vs baseline: 4.4632x; 1.0203x over previous
//
#include <hip/hip_runtime.h>
#include <hip/hip_bf16.h>
#include <math.h>

#define L_ 12
#define C_ 768
#define H_ 12
#define FF_ 3072
#define V_ 50257
#define VP_ 50304   // V padded to multiple of 128
#define T_ 512
#define B_ 4
#define D_ 64
#define M_ (B_*T_)   // 2048 rows
#define BH_ (B_*H_)  // 48
#define NPAN_LM 393  // VP_/128

typedef __attribute__((ext_vector_type(8))) short short8;
typedef __attribute__((ext_vector_type(4))) float f32x4;
typedef __attribute__((ext_vector_type(8))) unsigned short us8;

__device__ __forceinline__ float bf2f(unsigned short u) {
    return __uint_as_float(((unsigned)u) << 16);
}
__device__ __forceinline__ unsigned short f2bf(float f) {
    unsigned u = __float_as_uint(f);
    unsigned r = u + 0x7fff + ((u >> 16) & 1);   // RNE
    return (unsigned short)(r >> 16);
}

// ---------------- weight convert + transpose: W[K,N] fp32 -> WT[Npad,K] bf16 ----------------
__global__ __launch_bounds__(256) void transpose_bf16_kernel(
    const float* __restrict__ W, __hip_bfloat16* __restrict__ WT,
    int K, int N, int Npad)
{
    __shared__ float tile[64][65];
    const float* Wl = W + (size_t)blockIdx.z * K * N;
    __hip_bfloat16* WTl = WT + (size_t)blockIdx.z * Npad * K;
    int k0 = blockIdx.y * 64, n0 = blockIdx.x * 64;
    int tid = threadIdx.x;
    int tn = tid & 63, tk4 = tid >> 6;
#pragma unroll 4
    for (int i = 0; i < 16; ++i) {
        int k = tk4 * 16 + i;
        int n = n0 + tn;
        tile[k][tn] = (n < N) ? Wl[(size_t)(k0 + k) * N + n] : 0.f;
    }
    __syncthreads();
    // vectorized write: each task = one n, 8 consecutive k -> one us8 (16B) store
#pragma unroll
    for (int i = 0; i < 2; ++i) {
        int p = tid + i * 256;       // 0..511
        int n = p >> 3;              // 0..63
        int k8 = (p & 7) * 8;
        us8 v;
#pragma unroll
        for (int e = 0; e < 8; ++e) v[e] = f2bf(tile[k8 + e][n]);
        *(us8*)((unsigned short*)WTl + (size_t)(n0 + n) * K + k0 + k8) = v;
    }
}

// ---------------- embedding (fp32 residual stream) ----------------
__global__ void embed_kernel(const int* __restrict__ idx, const float* __restrict__ wte,
                             const float* __restrict__ wpe, float* __restrict__ x, int total)
{
    int i = blockIdx.x * blockDim.x + threadIdx.x;
    if (i >= total) return;
    int c = i % C_;
    int row = i / C_;
    int t = row % T_;
    x[i] = wte[(size_t)idx[row] * C_ + c] + wpe[(size_t)t * C_ + c];
}

// ---------------- layernorm: fp32 in, bf16 out ----------------
__global__ __launch_bounds__(256) void layernorm_kernel(
    const float* __restrict__ x, const float* __restrict__ w, const float* __restrict__ b,
    __hip_bfloat16* __restrict__ out)
{
    int row = blockIdx.x;
    int tid = threadIdx.x;
    const float* xr = x + (size_t)row * C_;
    float lx[3];
    float s = 0.f;
#pragma unroll
    for (int i = 0; i < 3; ++i) { lx[i] = xr[tid + i * 256]; s += lx[i]; }
    __shared__ float red[4];
    for (int off = 32; off > 0; off >>= 1) s += __shfl_down(s, off, 64);
    if ((tid & 63) == 0) red[tid >> 6] = s;
    __syncthreads();
    if (tid == 0) red[0] = red[0] + red[1] + red[2] + red[3];
    __syncthreads();
    float mean = red[0] * (1.f / (float)C_);
    __syncthreads();
    float v = 0.f;
#pragma unroll
    for (int i = 0; i < 3; ++i) { float d = lx[i] - mean; v += d * d; }
    for (int off = 32; off > 0; off >>= 1) v += __shfl_down(v, off, 64);
    if ((tid & 63) == 0) red[tid >> 6] = v;
    __syncthreads();
    if (tid == 0) red[0] = red[0] + red[1] + red[2] + red[3];
    __syncthreads();
    float rstd = rsqrtf(red[0] * (1.f / (float)C_) + 1e-5f);
#pragma unroll
    for (int i = 0; i < 3; ++i) {
        int c = tid + i * 256;
        ((unsigned short*)out)[(size_t)row * C_ + c] = f2bf((lx[i] - mean) * rstd * w[c] + b[c]);
    }
}

// ---------------- bf16 MFMA GEMM: C = A[M,K] @ Bt[N,K]^T (+bias)(+gelu)(+resid)(+loss partials) ----
template<int OUTBF, int GELU, int RESID, int LOSSP>
__global__ __launch_bounds__(256) void mfma_gemm(
    const __hip_bfloat16* __restrict__ A,
    const __hip_bfloat16* __restrict__ Bt,
    const float* __restrict__ bias,
    const float* __restrict__ resid,
    void* __restrict__ Cout,
    int M, int N, int K, int NB,
    float2* __restrict__ lpart, int NPAN)
{
    int ppx = (NB + 7) >> 3;
    int xcd = blockIdx.x & 7;
    int sidx = blockIdx.x >> 3;
    int npan = xcd * ppx + (sidx >> 4);
    int mpan = sidx & 15;
    if (npan >= NB) return;
    int m0 = mpan * 128, n0 = npan * 128;

    __shared__ __hip_bfloat16 As[128 * 32];
    __shared__ __hip_bfloat16 Bs[128 * 32];
    __shared__ float Lm[2][128], Lsum[2][128];
    int tid = threadIdx.x;
    int lane = tid & 63, w = tid >> 6;
    int wm = w >> 1, wn = w & 1;
    int lrow = lane & 15, lk = (lane >> 4) * 8;
    f32x4 acc[4][4] = {};

    const __hip_bfloat16* Ab = A + (size_t)m0 * K;
    const __hip_bfloat16* Bb = Bt + (size_t)n0 * K;

    for (int k0 = 0; k0 < K; k0 += 32) {
#pragma unroll
        for (int i = 0; i < 2; ++i) {
            int c = tid + i * 256;
            int row = c >> 2, kk = (c & 3) * 8;
            const __hip_bfloat16* ga = Ab + (size_t)row * K + k0 + kk;
            const __hip_bfloat16* gb = Bb + (size_t)row * K + k0 + kk;
            __builtin_amdgcn_global_load_lds(
                (const __attribute__((address_space(1))) void*)ga,
                (__attribute__((address_space(3))) void*)(&As[c * 8]), 16, 0, 0);
            __builtin_amdgcn_global_load_lds(
                (const __attribute__((address_space(1))) void*)gb,
                (__attribute__((address_space(3))) void*)(&Bs[c * 8]), 16, 0, 0);
        }
        __syncthreads();
        short8 a[4], b[4];
#pragma unroll
        for (int i = 0; i < 4; ++i)
            a[i] = *(const short8*)&As[(wm * 64 + i * 16 + lrow) * 32 + lk];
#pragma unroll
        for (int j = 0; j < 4; ++j)
            b[j] = *(const short8*)&Bs[(wn * 64 + j * 16 + lrow) * 32 + lk];
#pragma unroll
        for (int i = 0; i < 4; ++i)
#pragma unroll
            for (int j = 0; j < 4; ++j)
                acc[i][j] = __builtin_amdgcn_mfma_f32_16x16x32_bf16(a[i], b[j], acc[i][j], 0, 0, 0);
        __syncthreads();
    }
    int r0 = (lane >> 4) * 4;
#pragma unroll
    for (int i = 0; i < 4; ++i) {
#pragma unroll
        for (int j = 0; j < 4; ++j) {
            int col = n0 + wn * 64 + j * 16 + lrow;
            if (col >= N) continue;
            float bv = bias ? bias[col] : 0.f;
#pragma unroll
            for (int r = 0; r < 4; ++r) {
                int row = m0 + wm * 64 + i * 16 + r0 + r;
                float v = acc[i][j][r] + bv;
                if (GELU) {
                    float t = 0.7978845608028654f * (v + 0.044715f * v * v * v);
                    v = 0.5f * v * (1.f + tanhf(t));
                }
                if (RESID) v += resid[(size_t)row * N + col];
                if (OUTBF)
                    ((unsigned short*)Cout)[(size_t)row * N + col] = f2bf(v);
                else
                    ((float*)Cout)[(size_t)row * N + col] = v;
            }
        }
    }
    if (LOSSP) {
        // per-row online-softmax partials over this 128-col panel (no bias/gelu/resid path)
        int g = lane >> 4;
#pragma unroll
        for (int i = 0; i < 4; ++i) {
#pragma unroll
            for (int r = 0; r < 4; ++r) {
                float mx = -1e30f;
#pragma unroll
                for (int j = 0; j < 4; ++j) {
                    int col = n0 + wn * 64 + j * 16 + lrow;
                    if (col < V_) mx = fmaxf(mx, acc[i][j][r]);
                }
#pragma unroll
                for (int d2 = 1; d2 < 16; d2 <<= 1) mx = fmaxf(mx, __shfl_xor(mx, d2, 64));
                float ss = 0.f;
#pragma unroll
                for (int j = 0; j < 4; ++j) {
                    int col = n0 + wn * 64 + j * 16 + lrow;
                    if (col < V_) ss += __expf(acc[i][j][r] - mx);
                }
#pragma unroll
                for (int d2 = 1; d2 < 16; d2 <<= 1) ss += __shfl_xor(ss, d2, 64);
                if ((lane & 15) == 0) {
                    int rloc = wm * 64 + i * 16 + g * 4 + r;
                    Lm[wn][rloc] = mx;
                    Lsum[wn][rloc] = ss;
                }
            }
        }
        __syncthreads();
        if (tid < 128) {
            float m0v = Lm[0][tid], m1v = Lm[1][tid];
            float mm = fmaxf(m0v, m1v);
            float ss = Lsum[0][tid] * __expf(m0v - mm) + Lsum[1][tid] * __expf(m1v - mm);
            float2 out2; out2.x = mm; out2.y = ss;
            lpart[(size_t)(m0 + tid) * NPAN + npan] = out2;
        }
    }
}

// ---------------- qkv pack: Qp/Kp [BH][T][64], Vt [BH][64][T] ----------------
__global__ __launch_bounds__(256) void qkv_pack_kernel(
    const unsigned short* __restrict__ qkv,
    unsigned short* __restrict__ Qp, unsigned short* __restrict__ Kp,
    unsigned short* __restrict__ Vt)
{
    const int C3 = 3 * C_;
    int bx = blockIdx.x;
    int bh = bx >> 3;            // 0..47
    int t0 = (bx & 7) * 64;
    int b = bh / H_, h = bh % H_;
    const unsigned short* base = qkv + ((size_t)(b * T_ + t0)) * C3 + h * 64;
    int tid = threadIdx.x;
    __shared__ unsigned short vt_tile[64][72];
#pragma unroll
    for (int i = 0; i < 2; ++i) {
        int p = tid + i * 256;          // 0..511
        int row = p >> 3, cv = (p & 7) * 8;
        us8 q8 = *(const us8*)(base + (size_t)row * C3 + cv);
        *(us8*)(Qp + ((size_t)bh * T_ + t0 + row) * 64 + cv) = q8;
        us8 k8 = *(const us8*)(base + (size_t)row * C3 + C_ + cv);
        *(us8*)(Kp + ((size_t)bh * T_ + t0 + row) * 64 + cv) = k8;
        us8 v8 = *(const us8*)(base + (size_t)row * C3 + 2 * C_ + cv);
#pragma unroll
        for (int e = 0; e < 8; ++e) vt_tile[cv + e][row] = v8[e];
    }
    __syncthreads();
#pragma unroll
    for (int i = 0; i < 2; ++i) {
        int p = tid + i * 256;
        int d = p >> 3, tl = (p & 7) * 8;
        us8 o = *(const us8*)(&vt_tile[d][tl]);
        *(us8*)(Vt + ((size_t)bh * 64 + d) * T_ + t0 + tl) = o;
    }
}

// ---------------- MFMA flash attention: block = (bh, 16-row q-tile), 4 waves split KV ----------
// grid = 1536 blocks x 256 threads; wave w handles kv tiles t = w, w+4, ... (32 rows each),
// each wave keeps private (m,l,o); merged via LDS at the end (flash-decoding style).
__global__ __launch_bounds__(256) void flash_attn_kernel(
    const unsigned short* __restrict__ Qp, const unsigned short* __restrict__ Kp,
    const unsigned short* __restrict__ Vt, unsigned short* __restrict__ y)
{
    int bid = blockIdx.x;
    int xcd = bid & 7;
    int s_ = bid >> 3;                 // 0..191
    int bh = xcd * 6 + (s_ % 6);       // 6 heads per XCD for KV L2 locality
    int qi = s_ / 6;                   // 0..31
    int b = bh / H_, h = bh % H_;
    int q0 = qi * 16;
    int tid = threadIdx.x;
    int w = tid >> 6;
    int lane = tid & 63;
    int c = lane & 15, g = lane >> 4;

    const unsigned short* Qb = Qp + ((size_t)bh * T_ + q0) * 64;
    const unsigned short* Kb = Kp + (size_t)bh * T_ * 64;
    const unsigned short* Vb = Vt + (size_t)bh * 64 * T_;

    short8 qf0 = *(const short8*)(Qb + (size_t)c * 64 + g * 8);
    short8 qf1 = *(const short8*)(Qb + (size_t)c * 64 + 32 + g * 8);

    f32x4 o[4] = {};
    float mrow[4], lrow[4];
#pragma unroll
    for (int r = 0; r < 4; ++r) { mrow[r] = -1e30f; lrow[r] = 0.f; }

    __shared__ unsigned short P_lds[4][16 * 40];
    __shared__ float oW[4][16][64];
    __shared__ float mW[4][16], lW[4][16];

    int ntiles = q0 / 32 + 1;
    for (int t = w; t < ntiles; t += 4) {
        int kv0 = t * 32;
        f32x4 s[2] = {};
        __builtin_amdgcn_s_setprio(1);
#pragma unroll
        for (int tt = 0; tt < 2; ++tt) {
            const unsigned short* Kt = Kb + (size_t)(kv0 + tt * 16 + c) * 64;
            short8 b0 = *(const short8*)(Kt + g * 8);
            short8 b1 = *(const short8*)(Kt + 32 + g * 8);
            s[tt] = __builtin_amdgcn_mfma_f32_16x16x32_bf16(qf0, b0, s[tt], 0, 0, 0);
            s[tt] = __builtin_amdgcn_mfma_f32_16x16x32_bf16(qf1, b1, s[tt], 0, 0, 0);
        }
        __builtin_amdgcn_s_setprio(0);
        if (kv0 + 32 > q0) {
#pragma unroll
            for (int tt = 0; tt < 2; ++tt)
#pragma unroll
                for (int r = 0; r < 4; ++r) {
                    int kv = kv0 + tt * 16 + c;
                    int qq = q0 + g * 4 + r;
                    float v = s[tt][r] * 0.125f;
                    s[tt][r] = (kv <= qq) ? v : -1e30f;
                }
        } else {
#pragma unroll
            for (int tt = 0; tt < 2; ++tt)
#pragma unroll
                for (int r = 0; r < 4; ++r) s[tt][r] *= 0.125f;
        }
        float pmax[4];
#pragma unroll
        for (int r = 0; r < 4; ++r) pmax[r] = fmaxf(s[0][r], s[1][r]);
#pragma unroll
        for (int d2 = 1; d2 < 16; d2 <<= 1)
#pragma unroll
            for (int r = 0; r < 4; ++r) pmax[r] = fmaxf(pmax[r], __shfl_xor(pmax[r], d2, 64));
        float scl[4], psum[4];
#pragma unroll
        for (int r = 0; r < 4; ++r) {
            float mnew = fmaxf(mrow[r], pmax[r]);
            scl[r] = __expf(mrow[r] - mnew);
            mrow[r] = mnew;
            s[0][r] = __expf(s[0][r] - mnew);
            s[1][r] = __expf(s[1][r] - mnew);
            psum[r] = s[0][r] + s[1][r];
        }
#pragma unroll
        for (int d2 = 1; d2 < 16; d2 <<= 1)
#pragma unroll
            for (int r = 0; r < 4; ++r) psum[r] += __shfl_xor(psum[r], d2, 64);
#pragma unroll
        for (int r = 0; r < 4; ++r) lrow[r] = lrow[r] * scl[r] + psum[r];
#pragma unroll
        for (int j = 0; j < 4; ++j)
#pragma unroll
            for (int r = 0; r < 4; ++r) o[j][r] *= scl[r];
        // P -> per-wave LDS buffer (no block barrier: wave-private)
#pragma unroll
        for (int tt = 0; tt < 2; ++tt)
#pragma unroll
            for (int r = 0; r < 4; ++r)
                P_lds[w][(g * 4 + r) * 40 + tt * 16 + c] = f2bf(s[tt][r]);
        asm volatile("s_waitcnt lgkmcnt(0)" ::: "memory");
        __builtin_amdgcn_sched_barrier(0);
        short8 pf = *(const short8*)&P_lds[w][c * 40 + g * 8];
        asm volatile("s_waitcnt lgkmcnt(0)" ::: "memory");
        asm volatile("" ::: "memory");   // keep next iter's P writes after this read
        __builtin_amdgcn_s_setprio(1);
#pragma unroll
        for (int j = 0; j < 4; ++j) {
            short8 vf = *(const short8*)(Vb + (size_t)(j * 16 + c) * T_ + kv0 + g * 8);
            o[j] = __builtin_amdgcn_mfma_f32_16x16x32_bf16(pf, vf, o[j], 0, 0, 0);
        }
        __builtin_amdgcn_s_setprio(0);
    }
    // publish per-wave partials
    if (c == 0) {
#pragma unroll
        for (int r = 0; r < 4; ++r) { mW[w][g * 4 + r] = mrow[r]; lW[w][g * 4 + r] = lrow[r]; }
    }
#pragma unroll
    for (int j = 0; j < 4; ++j)
#pragma unroll
        for (int r = 0; r < 4; ++r) oW[w][g * 4 + r][j * 16 + c] = o[j][r];
    __syncthreads();
    // merge 4 wave-partials; thread -> (4 rows x 1 col)
    unsigned short* yb = y + ((size_t)(b * T_ + q0)) * C_ + h * 64;
    int col = tid & 63;
#pragma unroll
    for (int rr = 0; rr < 4; ++rr) {
        int row = (tid >> 6) * 4 + rr;   // 0..15
        float Mx = fmaxf(fmaxf(mW[0][row], mW[1][row]), fmaxf(mW[2][row], mW[3][row]));
        float Ls = 0.f, Os = 0.f;
#pragma unroll
        for (int ww = 0; ww < 4; ++ww) {
            float e = __expf(mW[ww][row] - Mx);
            Ls += lW[ww][row] * e;
            Os += oW[ww][row][col] * e;
        }
        yb[(size_t)row * C_ + col] = f2bf(Os / Ls);
    }
}

// ---------------- loss reduce over per-panel partials ----------------
__global__ __launch_bounds__(256) void loss_reduce_kernel(
    const float2* __restrict__ lpart, const float* __restrict__ logits,
    const int* __restrict__ targets, float* __restrict__ acc, int NPAN)
{
    int row = blockIdx.x;
    const float2* pp = lpart + (size_t)row * NPAN;
    int tid = threadIdx.x;
    float m = -1e30f, s = 0.f;
    for (int j = tid; j < NPAN; j += 256) {
        float2 p = pp[j];
        float mn = fmaxf(m, p.x);
        s = s * __expf(m - mn) + p.y * __expf(p.x - mn);
        m = mn;
    }
    for (int off = 32; off > 0; off >>= 1) {
        float mo = __shfl_down(m, off, 64);
        float so = __shfl_down(s, off, 64);
        float mn = fmaxf(m, mo);
        s = s * __expf(m - mn) + so * __expf(mo - mn);
        m = mn;
    }
    __shared__ float rm[4], rs[4];
    if ((tid & 63) == 0) { rm[tid >> 6] = m; rs[tid >> 6] = s; }
    __syncthreads();
    if (tid == 0) {
        float M = rm[0], S = rs[0];
        for (int i = 1; i < 4; ++i) {
            float mn = fmaxf(M, rm[i]);
            S = S * __expf(M - mn) + rs[i] * __expf(rm[i] - mn);
            M = mn;
        }
        int t = targets[row];
        if (t != -100) {
            float nll = -(logits[(size_t)row * V_ + t] - M - logf(S));
            atomicAdd(&acc[0], nll);
            atomicAdd(&acc[1], 1.f);
        }
    }
}

__global__ void finalize_loss(const float* __restrict__ acc, float* __restrict__ out)
{
    out[0] = acc[0] / fmaxf(acc[1], 1.f);
}

extern "C" void kernel_launch(void* const* d_in, const int* in_sizes, int n_in,
                              void* d_out, int out_size, void* d_ws, size_t ws_size,
                              hipStream_t stream)
{
    const int*   idx     = (const int*)d_in[0];
    const int*   targets = (const int*)d_in[1];
    const float* wte     = (const float*)d_in[2];
    const float* wpe     = (const float*)d_in[3];
    const float* ln1_w   = (const float*)d_in[4];
    const float* ln1_b   = (const float*)d_in[5];
    const float* attn_w  = (const float*)d_in[6];
    const float* attn_b  = (const float*)d_in[7];
    const float* attnp_w = (const float*)d_in[8];
    const float* attnp_b = (const float*)d_in[9];
    const float* ln2_w   = (const float*)d_in[10];
    const float* ln2_b   = (const float*)d_in[11];
    const float* fc_w    = (const float*)d_in[12];
    const float* fc_b    = (const float*)d_in[13];
    const float* fcp_w   = (const float*)d_in[14];
    const float* fcp_b   = (const float*)d_in[15];
    const float* lnf_w   = (const float*)d_in[16];
    const float* lnf_b   = (const float*)d_in[17];
    const float* lm_w    = (const float*)d_in[18];

    float* logits = (float*)d_out;                    // [M_, V_]
    float* loss   = logits + (size_t)M_ * V_;         // 1 float

    // ---- workspace layout ----
    char* p = (char*)d_ws;
    __hip_bfloat16* aw_t = (__hip_bfloat16*)p; p += (size_t)L_ * 3 * C_ * C_ * 2;
    __hip_bfloat16* pw_t = (__hip_bfloat16*)p; p += (size_t)L_ * C_ * C_ * 2;
    __hip_bfloat16* fw_t = (__hip_bfloat16*)p; p += (size_t)L_ * FF_ * C_ * 2;
    __hip_bfloat16* qw_t = (__hip_bfloat16*)p; p += (size_t)L_ * C_ * FF_ * 2;
    __hip_bfloat16* lm_t = (__hip_bfloat16*)p; p += (size_t)VP_ * C_ * 2;
    float*          x    = (float*)p;          p += (size_t)M_ * C_ * 4;
    __hip_bfloat16* h    = (__hip_bfloat16*)p; p += (size_t)M_ * C_ * 2;
    __hip_bfloat16* qkv  = (__hip_bfloat16*)p; p += (size_t)M_ * 3 * C_ * 2;
    __hip_bfloat16* y    = (__hip_bfloat16*)p; p += (size_t)M_ * C_ * 2;
    __hip_bfloat16* ff   = (__hip_bfloat16*)p; p += (size_t)M_ * FF_ * 2;
    unsigned short* Qp   = (unsigned short*)p; p += (size_t)BH_ * T_ * 64 * 2;
    unsigned short* Kp   = (unsigned short*)p; p += (size_t)BH_ * T_ * 64 * 2;
    unsigned short* Vt   = (unsigned short*)p; p += (size_t)BH_ * 64 * T_ * 2;
    float2*         lpart= (float2*)p;         p += (size_t)M_ * NPAN_LM * 8;
    float*          acc  = (float*)p;          p += 2 * 4;

    // ---- weight convert+transpose pre-pass ----
    transpose_bf16_kernel<<<dim3(3 * C_ / 64, C_ / 64, L_), 256, 0, stream>>>(attn_w, aw_t, C_, 3 * C_, 3 * C_);
    transpose_bf16_kernel<<<dim3(C_ / 64, C_ / 64, L_), 256, 0, stream>>>(attnp_w, pw_t, C_, C_, C_);
    transpose_bf16_kernel<<<dim3(FF_ / 64, C_ / 64, L_), 256, 0, stream>>>(fc_w, fw_t, C_, FF_, FF_);
    transpose_bf16_kernel<<<dim3(C_ / 64, FF_ / 64, L_), 256, 0, stream>>>(fcp_w, qw_t, FF_, C_, C_);
    transpose_bf16_kernel<<<dim3(VP_ / 64, C_ / 64, 1), 256, 0, stream>>>(lm_w, lm_t, C_, V_, VP_);

    // ---- embedding ----
    {
        int total = M_ * C_;
        embed_kernel<<<(total + 255) / 256, 256, 0, stream>>>(idx, wte, wpe, x, total);
    }

    #define GEMM_GRID(NB) (8 * (((NB) + 7) / 8) * 16)

    for (int l = 0; l < L_; ++l) {
        const float* l1w = ln1_w + (size_t)l * C_;
        const float* l1b = ln1_b + (size_t)l * C_;
        const __hip_bfloat16* aw = aw_t + (size_t)l * 3 * C_ * C_;
        const float* ab  = attn_b + (size_t)l * 3 * C_;
        const __hip_bfloat16* pw = pw_t + (size_t)l * C_ * C_;
        const float* pb  = attnp_b + (size_t)l * C_;
        const float* l2w = ln2_w + (size_t)l * C_;
        const float* l2b = ln2_b + (size_t)l * C_;
        const __hip_bfloat16* fw = fw_t + (size_t)l * FF_ * C_;
        const float* fb  = fc_b + (size_t)l * FF_;
        const __hip_bfloat16* qw = qw_t + (size_t)l * C_ * FF_;
        const float* qb  = fcp_b + (size_t)l * C_;

        layernorm_kernel<<<M_, 256, 0, stream>>>(x, l1w, l1b, h);
        mfma_gemm<1, 0, 0, 0><<<GEMM_GRID(18), 256, 0, stream>>>(
            h, aw, ab, nullptr, qkv, M_, 3 * C_, C_, 18, nullptr, 0);
        qkv_pack_kernel<<<BH_ * 8, 256, 0, stream>>>((const unsigned short*)qkv, Qp, Kp, Vt);
        flash_attn_kernel<<<8 * 6 * 32, 256, 0, stream>>>(Qp, Kp, Vt, (unsigned short*)y);
        mfma_gemm<0, 0, 1, 0><<<GEMM_GRID(6), 256, 0, stream>>>(
            y, pw, pb, x, x, M_, C_, C_, 6, nullptr, 0);
        layernorm_kernel<<<M_, 256, 0, stream>>>(x, l2w, l2b, h);
        mfma_gemm<1, 1, 0, 0><<<GEMM_GRID(24), 256, 0, stream>>>(
            h, fw, fb, nullptr, ff, M_, FF_, C_, 24, nullptr, 0);
        mfma_gemm<0, 0, 1, 0><<<GEMM_GRID(6), 256, 0, stream>>>(
            ff, qw, qb, x, x, M_, C_, FF_, 6, nullptr, 0);
    }

    layernorm_kernel<<<M_, 256, 0, stream>>>(x, lnf_w, lnf_b, h);
    mfma_gemm<0, 0, 0, 1><<<GEMM_GRID(NPAN_LM), 256, 0, stream>>>(
        h, lm_t, nullptr, nullptr, logits, M_, V_, C_, NPAN_LM, lpart, NPAN_LM);

    hipMemsetAsync(acc, 0, 2 * sizeof(float), stream);
    loss_reduce_kernel<<<M_, 256, 0, stream>>>(lpart, logits, targets, acc, NPAN_LM);
    finalize_loss<<<1, 1, 0, stream>>>(acc, loss);
}

// Round 5
// 3148.852 us; speedup vs baseline: 4.5969x; 1.0300x over previous
//
#include <hip/hip_runtime.h>
#include <hip/hip_bf16.h>
#include <math.h>

#define L_ 12
#define C_ 768
#define H_ 12
#define FF_ 3072
#define V_ 50257
#define VP_ 50304   // V padded to multiple of 128
#define T_ 512
#define B_ 4
#define D_ 64
#define M_ (B_*T_)   // 2048 rows
#define BH_ (B_*H_)  // 48
#define NPAN_LM 393  // VP_/128

typedef __attribute__((ext_vector_type(8))) short short8;
typedef __attribute__((ext_vector_type(4))) float f32x4;
typedef __attribute__((ext_vector_type(8))) unsigned short us8;

__device__ __forceinline__ float bf2f(unsigned short u) {
    return __uint_as_float(((unsigned)u) << 16);
}
__device__ __forceinline__ unsigned short f2bf(float f) {
    unsigned u = __float_as_uint(f);
    unsigned r = u + 0x7fff + ((u >> 16) & 1);   // RNE
    return (unsigned short)(r >> 16);
}

// ---------------- weight convert + transpose: W[K,N] fp32 -> WT[Npad,K] bf16 ----------------
__global__ __launch_bounds__(256) void transpose_bf16_kernel(
    const float* __restrict__ W, __hip_bfloat16* __restrict__ WT,
    int K, int N, int Npad)
{
    __shared__ float tile[64][65];
    const float* Wl = W + (size_t)blockIdx.z * K * N;
    __hip_bfloat16* WTl = WT + (size_t)blockIdx.z * Npad * K;
    int k0 = blockIdx.y * 64, n0 = blockIdx.x * 64;
    int tid = threadIdx.x;
    int tn = tid & 63, tk4 = tid >> 6;
#pragma unroll 4
    for (int i = 0; i < 16; ++i) {
        int k = tk4 * 16 + i;
        int n = n0 + tn;
        tile[k][tn] = (n < N) ? Wl[(size_t)(k0 + k) * N + n] : 0.f;
    }
    __syncthreads();
#pragma unroll
    for (int i = 0; i < 2; ++i) {
        int p = tid + i * 256;       // 0..511
        int n = p >> 3;              // 0..63
        int k8 = (p & 7) * 8;
        us8 v;
#pragma unroll
        for (int e = 0; e < 8; ++e) v[e] = f2bf(tile[k8 + e][n]);
        *(us8*)((unsigned short*)WTl + (size_t)(n0 + n) * K + k0 + k8) = v;
    }
}

// ---------------- embedding (fp32 residual stream) ----------------
__global__ void embed_kernel(const int* __restrict__ idx, const float* __restrict__ wte,
                             const float* __restrict__ wpe, float* __restrict__ x, int total)
{
    int i = blockIdx.x * blockDim.x + threadIdx.x;
    if (i >= total) return;
    int c = i % C_;
    int row = i / C_;
    int t = row % T_;
    x[i] = wte[(size_t)idx[row] * C_ + c] + wpe[(size_t)t * C_ + c];
}

// ---------------- layernorm: fp32 in, bf16 out ----------------
__global__ __launch_bounds__(256) void layernorm_kernel(
    const float* __restrict__ x, const float* __restrict__ w, const float* __restrict__ b,
    __hip_bfloat16* __restrict__ out)
{
    int row = blockIdx.x;
    int tid = threadIdx.x;
    const float* xr = x + (size_t)row * C_;
    float lx[3];
    float s = 0.f;
#pragma unroll
    for (int i = 0; i < 3; ++i) { lx[i] = xr[tid + i * 256]; s += lx[i]; }
    __shared__ float red[4];
    for (int off = 32; off > 0; off >>= 1) s += __shfl_down(s, off, 64);
    if ((tid & 63) == 0) red[tid >> 6] = s;
    __syncthreads();
    if (tid == 0) red[0] = red[0] + red[1] + red[2] + red[3];
    __syncthreads();
    float mean = red[0] * (1.f / (float)C_);
    __syncthreads();
    float v = 0.f;
#pragma unroll
    for (int i = 0; i < 3; ++i) { float d = lx[i] - mean; v += d * d; }
    for (int off = 32; off > 0; off >>= 1) v += __shfl_down(v, off, 64);
    if ((tid & 63) == 0) red[tid >> 6] = v;
    __syncthreads();
    if (tid == 0) red[0] = red[0] + red[1] + red[2] + red[3];
    __syncthreads();
    float rstd = rsqrtf(red[0] * (1.f / (float)C_) + 1e-5f);
#pragma unroll
    for (int i = 0; i < 3; ++i) {
        int c = tid + i * 256;
        ((unsigned short*)out)[(size_t)row * C_ + c] = f2bf((lx[i] - mean) * rstd * w[c] + b[c]);
    }
}

// ---------------- bf16 MFMA GEMM, pipelined (T3+T4): 3-buffer LDS, depth-2 prefetch, ------
// counted vmcnt(4), one s_barrier per K-step. 128x128 tile, BK=32, 4 waves.
// Epilogue variants: bias/gelu/resid/loss-partials/qkv-pack.
template<int OUTBF, int GELU, int RESID, int LOSSP, int QKVPACK>
__global__ __launch_bounds__(256) void mfma_gemm(
    const __hip_bfloat16* __restrict__ A,
    const __hip_bfloat16* __restrict__ Bt,
    const float* __restrict__ bias,
    const float* __restrict__ resid,
    void* __restrict__ Cout,
    int M, int N, int K, int NB,
    float2* __restrict__ lpart, int NPAN,
    unsigned short* __restrict__ Qp, unsigned short* __restrict__ Kp,
    unsigned short* __restrict__ Vt)
{
    int ppx = (NB + 7) >> 3;
    int xcd = blockIdx.x & 7;
    int sidx = blockIdx.x >> 3;
    int npan = xcd * ppx + (sidx >> 4);
    int mpan = sidx & 15;
    if (npan >= NB) return;
    int m0 = mpan * 128, n0 = npan * 128;

    __shared__ __hip_bfloat16 As[3][128 * 32];
    __shared__ __hip_bfloat16 Bs[3][128 * 32];
    __shared__ float Lm[2][128], Lsum[2][128];
    int tid = threadIdx.x;
    int lane = tid & 63, w = tid >> 6;
    int wm = w >> 1, wn = w & 1;
    int lrow = lane & 15, lk = (lane >> 4) * 8;
    f32x4 acc[4][4] = {};

    const __hip_bfloat16* Ab = A + (size_t)m0 * K;
    const __hip_bfloat16* Bb = Bt + (size_t)n0 * K;

    auto stage = [&](int buf, int k0) {
#pragma unroll
        for (int i = 0; i < 2; ++i) {
            int c = tid + i * 256;
            int row = c >> 2, kk = (c & 3) * 8;
            __builtin_amdgcn_global_load_lds(
                (const __attribute__((address_space(1))) void*)(Ab + (size_t)row * K + k0 + kk),
                (__attribute__((address_space(3))) void*)(&As[buf][c * 8]), 16, 0, 0);
            __builtin_amdgcn_global_load_lds(
                (const __attribute__((address_space(1))) void*)(Bb + (size_t)row * K + k0 + kk),
                (__attribute__((address_space(3))) void*)(&Bs[buf][c * 8]), 16, 0, 0);
        }
    };
    auto do_tile = [&](int buf) {
        short8 a[4], b[4];
#pragma unroll
        for (int i = 0; i < 4; ++i)
            a[i] = *(const short8*)&As[buf][(wm * 64 + i * 16 + lrow) * 32 + lk];
#pragma unroll
        for (int j = 0; j < 4; ++j)
            b[j] = *(const short8*)&Bs[buf][(wn * 64 + j * 16 + lrow) * 32 + lk];
        asm volatile("s_waitcnt lgkmcnt(0)" ::: "memory");
        __builtin_amdgcn_sched_barrier(0);
        __builtin_amdgcn_s_setprio(1);
#pragma unroll
        for (int i = 0; i < 4; ++i)
#pragma unroll
            for (int j = 0; j < 4; ++j)
                acc[i][j] = __builtin_amdgcn_mfma_f32_16x16x32_bf16(a[i], b[j], acc[i][j], 0, 0, 0);
        __builtin_amdgcn_s_setprio(0);
    };

    int nk = K >> 5;
    stage(0, 0);
    stage(1, 32);
    for (int t = 0; t < nk - 1; ++t) {
        asm volatile("s_waitcnt vmcnt(4)" ::: "memory");   // tile t landed; t+1 in flight
        __builtin_amdgcn_s_barrier();
        if (t + 2 < nk) stage((t + 2) % 3, (t + 2) << 5);  // overlap with compute below
        do_tile(t % 3);
    }
    asm volatile("s_waitcnt vmcnt(0)" ::: "memory");
    __builtin_amdgcn_s_barrier();
    do_tile((nk - 1) % 3);

    int r0 = (lane >> 4) * 4;
#pragma unroll
    for (int i = 0; i < 4; ++i) {
#pragma unroll
        for (int j = 0; j < 4; ++j) {
            int col = n0 + wn * 64 + j * 16 + lrow;
            if (col >= N) continue;
            float bv = bias ? bias[col] : 0.f;
#pragma unroll
            for (int r = 0; r < 4; ++r) {
                int row = m0 + wm * 64 + i * 16 + r0 + r;
                float v = acc[i][j][r] + bv;
                if (GELU) {
                    float t = 0.7978845608028654f * (v + 0.044715f * v * v * v);
                    v = 0.5f * v * (1.f + tanhf(t));
                }
                if (RESID) v += resid[(size_t)row * N + col];
                if (QKVPACK) {
                    int bb = row >> 9, tt = row & (T_ - 1);
                    int which = col / 768;
                    int cc = col - which * 768;
                    int hh = cc >> 6, d = cc & 63;
                    size_t bh = (size_t)bb * H_ + hh;
                    unsigned short u = f2bf(v);
                    if (which == 0)      Qp[(bh * T_ + tt) * 64 + d] = u;
                    else if (which == 1) Kp[(bh * T_ + tt) * 64 + d] = u;
                    else                 Vt[(bh * 64 + d) * T_ + tt] = u;
                } else if (OUTBF) {
                    ((unsigned short*)Cout)[(size_t)row * N + col] = f2bf(v);
                } else {
                    ((float*)Cout)[(size_t)row * N + col] = v;
                }
            }
        }
    }
    if (LOSSP) {
        int g = lane >> 4;
#pragma unroll
        for (int i = 0; i < 4; ++i) {
#pragma unroll
            for (int r = 0; r < 4; ++r) {
                float mx = -1e30f;
#pragma unroll
                for (int j = 0; j < 4; ++j) {
                    int col = n0 + wn * 64 + j * 16 + lrow;
                    if (col < V_) mx = fmaxf(mx, acc[i][j][r]);
                }
#pragma unroll
                for (int d2 = 1; d2 < 16; d2 <<= 1) mx = fmaxf(mx, __shfl_xor(mx, d2, 64));
                float ss = 0.f;
#pragma unroll
                for (int j = 0; j < 4; ++j) {
                    int col = n0 + wn * 64 + j * 16 + lrow;
                    if (col < V_) ss += __expf(acc[i][j][r] - mx);
                }
#pragma unroll
                for (int d2 = 1; d2 < 16; d2 <<= 1) ss += __shfl_xor(ss, d2, 64);
                if ((lane & 15) == 0) {
                    int rloc = wm * 64 + i * 16 + g * 4 + r;
                    Lm[wn][rloc] = mx;
                    Lsum[wn][rloc] = ss;
                }
            }
        }
        __syncthreads();
        if (tid < 128) {
            float m0v = Lm[0][tid], m1v = Lm[1][tid];
            float mm = fmaxf(m0v, m1v);
            float ss = Lsum[0][tid] * __expf(m0v - mm) + Lsum[1][tid] * __expf(m1v - mm);
            float2 out2; out2.x = mm; out2.y = ss;
            lpart[(size_t)(m0 + tid) * NPAN + npan] = out2;
        }
    }
}

// ---------------- MFMA flash attention: block = (bh, 16-row q-tile), 4 waves split KV ----------
__global__ __launch_bounds__(256) void flash_attn_kernel(
    const unsigned short* __restrict__ Qp, const unsigned short* __restrict__ Kp,
    const unsigned short* __restrict__ Vt, unsigned short* __restrict__ y)
{
    int bid = blockIdx.x;
    int xcd = bid & 7;
    int s_ = bid >> 3;                 // 0..191
    int bh = xcd * 6 + (s_ % 6);       // 6 heads per XCD for KV L2 locality
    int qi = s_ / 6;                   // 0..31
    int b = bh / H_, h = bh % H_;
    int q0 = qi * 16;
    int tid = threadIdx.x;
    int w = tid >> 6;
    int lane = tid & 63;
    int c = lane & 15, g = lane >> 4;

    const unsigned short* Qb = Qp + ((size_t)bh * T_ + q0) * 64;
    const unsigned short* Kb = Kp + (size_t)bh * T_ * 64;
    const unsigned short* Vb = Vt + (size_t)bh * 64 * T_;

    short8 qf0 = *(const short8*)(Qb + (size_t)c * 64 + g * 8);
    short8 qf1 = *(const short8*)(Qb + (size_t)c * 64 + 32 + g * 8);

    f32x4 o[4] = {};
    float mrow[4], lrow[4];
#pragma unroll
    for (int r = 0; r < 4; ++r) { mrow[r] = -1e30f; lrow[r] = 0.f; }

    __shared__ unsigned short P_lds[4][16 * 40];
    __shared__ float oW[4][16][64];
    __shared__ float mW[4][16], lW[4][16];

    int ntiles = q0 / 32 + 1;
    for (int t = w; t < ntiles; t += 4) {
        int kv0 = t * 32;
        f32x4 s[2] = {};
        __builtin_amdgcn_s_setprio(1);
#pragma unroll
        for (int tt = 0; tt < 2; ++tt) {
            const unsigned short* Kt = Kb + (size_t)(kv0 + tt * 16 + c) * 64;
            short8 b0 = *(const short8*)(Kt + g * 8);
            short8 b1 = *(const short8*)(Kt + 32 + g * 8);
            s[tt] = __builtin_amdgcn_mfma_f32_16x16x32_bf16(qf0, b0, s[tt], 0, 0, 0);
            s[tt] = __builtin_amdgcn_mfma_f32_16x16x32_bf16(qf1, b1, s[tt], 0, 0, 0);
        }
        __builtin_amdgcn_s_setprio(0);
        if (kv0 + 32 > q0) {
#pragma unroll
            for (int tt = 0; tt < 2; ++tt)
#pragma unroll
                for (int r = 0; r < 4; ++r) {
                    int kv = kv0 + tt * 16 + c;
                    int qq = q0 + g * 4 + r;
                    float v = s[tt][r] * 0.125f;
                    s[tt][r] = (kv <= qq) ? v : -1e30f;
                }
        } else {
#pragma unroll
            for (int tt = 0; tt < 2; ++tt)
#pragma unroll
                for (int r = 0; r < 4; ++r) s[tt][r] *= 0.125f;
        }
        float pmax[4];
#pragma unroll
        for (int r = 0; r < 4; ++r) pmax[r] = fmaxf(s[0][r], s[1][r]);
#pragma unroll
        for (int d2 = 1; d2 < 16; d2 <<= 1)
#pragma unroll
            for (int r = 0; r < 4; ++r) pmax[r] = fmaxf(pmax[r], __shfl_xor(pmax[r], d2, 64));
        float scl[4], psum[4];
#pragma unroll
        for (int r = 0; r < 4; ++r) {
            float mnew = fmaxf(mrow[r], pmax[r]);
            scl[r] = __expf(mrow[r] - mnew);
            mrow[r] = mnew;
            s[0][r] = __expf(s[0][r] - mnew);
            s[1][r] = __expf(s[1][r] - mnew);
            psum[r] = s[0][r] + s[1][r];
        }
#pragma unroll
        for (int d2 = 1; d2 < 16; d2 <<= 1)
#pragma unroll
            for (int r = 0; r < 4; ++r) psum[r] += __shfl_xor(psum[r], d2, 64);
#pragma unroll
        for (int r = 0; r < 4; ++r) lrow[r] = lrow[r] * scl[r] + psum[r];
#pragma unroll
        for (int j = 0; j < 4; ++j)
#pragma unroll
            for (int r = 0; r < 4; ++r) o[j][r] *= scl[r];
#pragma unroll
        for (int tt = 0; tt < 2; ++tt)
#pragma unroll
            for (int r = 0; r < 4; ++r)
                P_lds[w][(g * 4 + r) * 40 + tt * 16 + c] = f2bf(s[tt][r]);
        asm volatile("s_waitcnt lgkmcnt(0)" ::: "memory");
        __builtin_amdgcn_sched_barrier(0);
        short8 pf = *(const short8*)&P_lds[w][c * 40 + g * 8];
        asm volatile("s_waitcnt lgkmcnt(0)" ::: "memory");
        asm volatile("" ::: "memory");
        __builtin_amdgcn_s_setprio(1);
#pragma unroll
        for (int j = 0; j < 4; ++j) {
            short8 vf = *(const short8*)(Vb + (size_t)(j * 16 + c) * T_ + kv0 + g * 8);
            o[j] = __builtin_amdgcn_mfma_f32_16x16x32_bf16(pf, vf, o[j], 0, 0, 0);
        }
        __builtin_amdgcn_s_setprio(0);
    }
    if (c == 0) {
#pragma unroll
        for (int r = 0; r < 4; ++r) { mW[w][g * 4 + r] = mrow[r]; lW[w][g * 4 + r] = lrow[r]; }
    }
#pragma unroll
    for (int j = 0; j < 4; ++j)
#pragma unroll
        for (int r = 0; r < 4; ++r) oW[w][g * 4 + r][j * 16 + c] = o[j][r];
    __syncthreads();
    unsigned short* yb = y + ((size_t)(b * T_ + q0)) * C_ + h * 64;
    int col = tid & 63;
#pragma unroll
    for (int rr = 0; rr < 4; ++rr) {
        int row = (tid >> 6) * 4 + rr;   // 0..15
        float Mx = fmaxf(fmaxf(mW[0][row], mW[1][row]), fmaxf(mW[2][row], mW[3][row]));
        float Ls = 0.f, Os = 0.f;
#pragma unroll
        for (int ww = 0; ww < 4; ++ww) {
            float e = __expf(mW[ww][row] - Mx);
            Ls += lW[ww][row] * e;
            Os += oW[ww][row][col] * e;
        }
        yb[(size_t)row * C_ + col] = f2bf(Os / Ls);
    }
}

// ---------------- loss reduce over per-panel partials ----------------
__global__ __launch_bounds__(256) void loss_reduce_kernel(
    const float2* __restrict__ lpart, const float* __restrict__ logits,
    const int* __restrict__ targets, float* __restrict__ acc, int NPAN)
{
    int row = blockIdx.x;
    const float2* pp = lpart + (size_t)row * NPAN;
    int tid = threadIdx.x;
    float m = -1e30f, s = 0.f;
    for (int j = tid; j < NPAN; j += 256) {
        float2 p = pp[j];
        float mn = fmaxf(m, p.x);
        s = s * __expf(m - mn) + p.y * __expf(p.x - mn);
        m = mn;
    }
    for (int off = 32; off > 0; off >>= 1) {
        float mo = __shfl_down(m, off, 64);
        float so = __shfl_down(s, off, 64);
        float mn = fmaxf(m, mo);
        s = s * __expf(m - mn) + so * __expf(mo - mn);
        m = mn;
    }
    __shared__ float rm[4], rs[4];
    if ((tid & 63) == 0) { rm[tid >> 6] = m; rs[tid >> 6] = s; }
    __syncthreads();
    if (tid == 0) {
        float M = rm[0], S = rs[0];
        for (int i = 1; i < 4; ++i) {
            float mn = fmaxf(M, rm[i]);
            S = S * __expf(M - mn) + rs[i] * __expf(rm[i] - mn);
            M = mn;
        }
        int t = targets[row];
        if (t != -100) {
            float nll = -(logits[(size_t)row * V_ + t] - M - logf(S));
            atomicAdd(&acc[0], nll);
            atomicAdd(&acc[1], 1.f);
        }
    }
}

__global__ void finalize_loss(const float* __restrict__ acc, float* __restrict__ out)
{
    out[0] = acc[0] / fmaxf(acc[1], 1.f);
}

extern "C" void kernel_launch(void* const* d_in, const int* in_sizes, int n_in,
                              void* d_out, int out_size, void* d_ws, size_t ws_size,
                              hipStream_t stream)
{
    const int*   idx     = (const int*)d_in[0];
    const int*   targets = (const int*)d_in[1];
    const float* wte     = (const float*)d_in[2];
    const float* wpe     = (const float*)d_in[3];
    const float* ln1_w   = (const float*)d_in[4];
    const float* ln1_b   = (const float*)d_in[5];
    const float* attn_w  = (const float*)d_in[6];
    const float* attn_b  = (const float*)d_in[7];
    const float* attnp_w = (const float*)d_in[8];
    const float* attnp_b = (const float*)d_in[9];
    const float* ln2_w   = (const float*)d_in[10];
    const float* ln2_b   = (const float*)d_in[11];
    const float* fc_w    = (const float*)d_in[12];
    const float* fc_b    = (const float*)d_in[13];
    const float* fcp_w   = (const float*)d_in[14];
    const float* fcp_b   = (const float*)d_in[15];
    const float* lnf_w   = (const float*)d_in[16];
    const float* lnf_b   = (const float*)d_in[17];
    const float* lm_w    = (const float*)d_in[18];

    float* logits = (float*)d_out;                    // [M_, V_]
    float* loss   = logits + (size_t)M_ * V_;         // 1 float

    // ---- workspace layout ----
    char* p = (char*)d_ws;
    __hip_bfloat16* aw_t = (__hip_bfloat16*)p; p += (size_t)L_ * 3 * C_ * C_ * 2;
    __hip_bfloat16* pw_t = (__hip_bfloat16*)p; p += (size_t)L_ * C_ * C_ * 2;
    __hip_bfloat16* fw_t = (__hip_bfloat16*)p; p += (size_t)L_ * FF_ * C_ * 2;
    __hip_bfloat16* qw_t = (__hip_bfloat16*)p; p += (size_t)L_ * C_ * FF_ * 2;
    __hip_bfloat16* lm_t = (__hip_bfloat16*)p; p += (size_t)VP_ * C_ * 2;
    float*          x    = (float*)p;          p += (size_t)M_ * C_ * 4;
    __hip_bfloat16* h    = (__hip_bfloat16*)p; p += (size_t)M_ * C_ * 2;
    __hip_bfloat16* y    = (__hip_bfloat16*)p; p += (size_t)M_ * C_ * 2;
    __hip_bfloat16* ff   = (__hip_bfloat16*)p; p += (size_t)M_ * FF_ * 2;
    unsigned short* Qp   = (unsigned short*)p; p += (size_t)BH_ * T_ * 64 * 2;
    unsigned short* Kp   = (unsigned short*)p; p += (size_t)BH_ * T_ * 64 * 2;
    unsigned short* Vt   = (unsigned short*)p; p += (size_t)BH_ * 64 * T_ * 2;
    float2*         lpart= (float2*)p;         p += (size_t)M_ * NPAN_LM * 8;
    float*          acc  = (float*)p;          p += 2 * 4;

    // ---- weight convert+transpose pre-pass ----
    transpose_bf16_kernel<<<dim3(3 * C_ / 64, C_ / 64, L_), 256, 0, stream>>>(attn_w, aw_t, C_, 3 * C_, 3 * C_);
    transpose_bf16_kernel<<<dim3(C_ / 64, C_ / 64, L_), 256, 0, stream>>>(attnp_w, pw_t, C_, C_, C_);
    transpose_bf16_kernel<<<dim3(FF_ / 64, C_ / 64, L_), 256, 0, stream>>>(fc_w, fw_t, C_, FF_, FF_);
    transpose_bf16_kernel<<<dim3(C_ / 64, FF_ / 64, L_), 256, 0, stream>>>(fcp_w, qw_t, FF_, C_, C_);
    transpose_bf16_kernel<<<dim3(VP_ / 64, C_ / 64, 1), 256, 0, stream>>>(lm_w, lm_t, C_, V_, VP_);

    // ---- embedding ----
    {
        int total = M_ * C_;
        embed_kernel<<<(total + 255) / 256, 256, 0, stream>>>(idx, wte, wpe, x, total);
    }

    #define GEMM_GRID(NB) (8 * (((NB) + 7) / 8) * 16)

    for (int l = 0; l < L_; ++l) {
        const float* l1w = ln1_w + (size_t)l * C_;
        const float* l1b = ln1_b + (size_t)l * C_;
        const __hip_bfloat16* aw = aw_t + (size_t)l * 3 * C_ * C_;
        const float* ab  = attn_b + (size_t)l * 3 * C_;
        const __hip_bfloat16* pw = pw_t + (size_t)l * C_ * C_;
        const float* pb  = attnp_b + (size_t)l * C_;
        const float* l2w = ln2_w + (size_t)l * C_;
        const float* l2b = ln2_b + (size_t)l * C_;
        const __hip_bfloat16* fw = fw_t + (size_t)l * FF_ * C_;
        const float* fb  = fc_b + (size_t)l * FF_;
        const __hip_bfloat16* qw = qw_t + (size_t)l * C_ * FF_;
        const float* qb  = fcp_b + (size_t)l * C_;

        layernorm_kernel<<<M_, 256, 0, stream>>>(x, l1w, l1b, h);
        // qkv GEMM with fused head-pack epilogue
        mfma_gemm<0, 0, 0, 0, 1><<<GEMM_GRID(18), 256, 0, stream>>>(
            h, aw, ab, nullptr, nullptr, M_, 3 * C_, C_, 18, nullptr, 0, Qp, Kp, Vt);
        flash_attn_kernel<<<8 * 6 * 32, 256, 0, stream>>>(Qp, Kp, Vt, (unsigned short*)y);
        mfma_gemm<0, 0, 1, 0, 0><<<GEMM_GRID(6), 256, 0, stream>>>(
            y, pw, pb, x, x, M_, C_, C_, 6, nullptr, 0, nullptr, nullptr, nullptr);
        layernorm_kernel<<<M_, 256, 0, stream>>>(x, l2w, l2b, h);
        mfma_gemm<1, 1, 0, 0, 0><<<GEMM_GRID(24), 256, 0, stream>>>(
            h, fw, fb, nullptr, ff, M_, FF_, C_, 24, nullptr, 0, nullptr, nullptr, nullptr);
        mfma_gemm<0, 0, 1, 0, 0><<<GEMM_GRID(6), 256, 0, stream>>>(
            ff, qw, qb, x, x, M_, C_, FF_, 6, nullptr, 0, nullptr, nullptr, nullptr);
    }

    layernorm_kernel<<<M_, 256, 0, stream>>>(x, lnf_w, lnf_b, h);
    mfma_gemm<0, 0, 0, 1, 0><<<GEMM_GRID(NPAN_LM), 256, 0, stream>>>(
        h, lm_t, nullptr, nullptr, logits, M_, V_, C_, NPAN_LM, lpart, NPAN_LM,
        nullptr, nullptr, nullptr);

    hipMemsetAsync(acc, 0, 2 * sizeof(float), stream);
    loss_reduce_kernel<<<M_, 256, 0, stream>>>(lpart, logits, targets, acc, NPAN_LM);
    finalize_loss<<<1, 1, 0, stream>>>(acc, loss);
}

// Round 6
// 2898.561 us; speedup vs baseline: 4.9939x; 1.0863x over previous
//
#include <hip/hip_runtime.h>
#include <hip/hip_bf16.h>
#include <math.h>

#define L_ 12
#define C_ 768
#define H_ 12
#define FF_ 3072
#define V_ 50257
#define VP_ 50304   // V padded to multiple of 128
#define T_ 512
#define B_ 4
#define D_ 64
#define M_ (B_*T_)   // 2048 rows
#define BH_ (B_*H_)  // 48
#define NPAN_LM 393  // VP_/128

typedef __attribute__((ext_vector_type(8))) short short8;
typedef __attribute__((ext_vector_type(4))) float f32x4;
typedef __attribute__((ext_vector_type(8))) unsigned short us8;

__device__ __forceinline__ float bf2f(unsigned short u) {
    return __uint_as_float(((unsigned)u) << 16);
}
__device__ __forceinline__ unsigned short f2bf(float f) {
    unsigned u = __float_as_uint(f);
    unsigned r = u + 0x7fff + ((u >> 16) & 1);   // RNE
    return (unsigned short)(r >> 16);
}

// ---------------- weight convert + transpose: W[K,N] fp32 -> WT[Npad,K] bf16 ----------------
__global__ __launch_bounds__(256) void transpose_bf16_kernel(
    const float* __restrict__ W, __hip_bfloat16* __restrict__ WT,
    int K, int N, int Npad)
{
    __shared__ float tile[64][65];
    const float* Wl = W + (size_t)blockIdx.z * K * N;
    __hip_bfloat16* WTl = WT + (size_t)blockIdx.z * Npad * K;
    int k0 = blockIdx.y * 64, n0 = blockIdx.x * 64;
    int tid = threadIdx.x;
    int tn = tid & 63, tk4 = tid >> 6;
#pragma unroll 4
    for (int i = 0; i < 16; ++i) {
        int k = tk4 * 16 + i;
        int n = n0 + tn;
        tile[k][tn] = (n < N) ? Wl[(size_t)(k0 + k) * N + n] : 0.f;
    }
    __syncthreads();
#pragma unroll
    for (int i = 0; i < 2; ++i) {
        int p = tid + i * 256;       // 0..511
        int n = p >> 3;              // 0..63
        int k8 = (p & 7) * 8;
        us8 v;
#pragma unroll
        for (int e = 0; e < 8; ++e) v[e] = f2bf(tile[k8 + e][n]);
        *(us8*)((unsigned short*)WTl + (size_t)(n0 + n) * K + k0 + k8) = v;
    }
}

// ---------------- embedding (fp32 residual stream) ----------------
__global__ void embed_kernel(const int* __restrict__ idx, const float* __restrict__ wte,
                             const float* __restrict__ wpe, float* __restrict__ x, int total)
{
    int i = blockIdx.x * blockDim.x + threadIdx.x;
    if (i >= total) return;
    int c = i % C_;
    int row = i / C_;
    int t = row % T_;
    x[i] = wte[(size_t)idx[row] * C_ + c] + wpe[(size_t)t * C_ + c];
}

// ---------------- layernorm: fp32 in, bf16 out ----------------
__global__ __launch_bounds__(256) void layernorm_kernel(
    const float* __restrict__ x, const float* __restrict__ w, const float* __restrict__ b,
    __hip_bfloat16* __restrict__ out)
{
    int row = blockIdx.x;
    int tid = threadIdx.x;
    const float* xr = x + (size_t)row * C_;
    float lx[3];
    float s = 0.f;
#pragma unroll
    for (int i = 0; i < 3; ++i) { lx[i] = xr[tid + i * 256]; s += lx[i]; }
    __shared__ float red[4];
    for (int off = 32; off > 0; off >>= 1) s += __shfl_down(s, off, 64);
    if ((tid & 63) == 0) red[tid >> 6] = s;
    __syncthreads();
    if (tid == 0) red[0] = red[0] + red[1] + red[2] + red[3];
    __syncthreads();
    float mean = red[0] * (1.f / (float)C_);
    __syncthreads();
    float v = 0.f;
#pragma unroll
    for (int i = 0; i < 3; ++i) { float d = lx[i] - mean; v += d * d; }
    for (int off = 32; off > 0; off >>= 1) v += __shfl_down(v, off, 64);
    if ((tid & 63) == 0) red[tid >> 6] = v;
    __syncthreads();
    if (tid == 0) red[0] = red[0] + red[1] + red[2] + red[3];
    __syncthreads();
    float rstd = rsqrtf(red[0] * (1.f / (float)C_) + 1e-5f);
#pragma unroll
    for (int i = 0; i < 3; ++i) {
        int c = tid + i * 256;
        ((unsigned short*)out)[(size_t)row * C_ + c] = f2bf((lx[i] - mean) * rstd * w[c] + b[c]);
    }
}

// ---------------- bf16 MFMA GEMM, pipelined + LDS-swizzled ----------------
// MT x 128 tile (MT = 128 or 64), BK=32, 3-buffer LDS, depth-2 prefetch, counted vmcnt.
// Swizzle (T2/G21): LDS dest linear; global source slot l = (s - (row>>1)) & 3;
// ds_read phys slot s = (g + (row>>1)) & 3. Rows 0..7 -> 8 distinct 4-bank sets.
template<int MT, int OUTBF, int GELU, int RESID, int LOSSP, int QKVPACK>
__global__ __launch_bounds__(256) void mfma_gemm(
    const __hip_bfloat16* __restrict__ A,
    const __hip_bfloat16* __restrict__ Bt,
    const float* __restrict__ bias,
    const float* __restrict__ resid,
    void* __restrict__ Cout,
    int M, int N, int K, int NB,
    float2* __restrict__ lpart, int NPAN,
    unsigned short* __restrict__ Qp, unsigned short* __restrict__ Kp,
    unsigned short* __restrict__ Vt)
{
    constexpr int MPAN = M_ / MT;      // m-panels
    constexpr int MFR  = MT / 32;      // per-wave m-fragments (4 or 2)
    int ppx = (NB + 7) >> 3;
    int xcd = blockIdx.x & 7;
    int sidx = blockIdx.x >> 3;
    int npan = xcd * ppx + sidx / MPAN;
    int mpan = sidx % MPAN;
    if (npan >= NB) return;
    int m0 = mpan * MT, n0 = npan * 128;

    __shared__ __hip_bfloat16 As[3][MT * 32];
    __shared__ __hip_bfloat16 Bs[3][128 * 32];
    __shared__ float Lm[2][LOSSP ? 128 : 1], Lsum[2][LOSSP ? 128 : 1];
    int tid = threadIdx.x;
    int lane = tid & 63, w = tid >> 6;
    int wm = w >> 1, wn = w & 1;
    int lrow = lane & 15, g = lane >> 4;
    f32x4 acc[MFR][4] = {};

    const __hip_bfloat16* Ab = A + (size_t)m0 * K;
    const __hip_bfloat16* Bb = Bt + (size_t)n0 * K;

    auto stage = [&](int buf, int k0) {
#pragma unroll
        for (int i = 0; i < MT / 64; ++i) {          // A: MT rows
            int c = tid + i * 256;
            int row = c >> 2, s = c & 3;
            int l = (s - (row >> 1)) & 3;            // inverse-swizzled source slot
            __builtin_amdgcn_global_load_lds(
                (const __attribute__((address_space(1))) void*)(Ab + (size_t)row * K + k0 + l * 8),
                (__attribute__((address_space(3))) void*)(&As[buf][c * 8]), 16, 0, 0);
        }
#pragma unroll
        for (int i = 0; i < 2; ++i) {                // B: 128 rows
            int c = tid + i * 256;
            int row = c >> 2, s = c & 3;
            int l = (s - (row >> 1)) & 3;
            __builtin_amdgcn_global_load_lds(
                (const __attribute__((address_space(1))) void*)(Bb + (size_t)row * K + k0 + l * 8),
                (__attribute__((address_space(3))) void*)(&Bs[buf][c * 8]), 16, 0, 0);
        }
    };
    auto do_tile = [&](int buf) {
        short8 a[MFR], b[4];
#pragma unroll
        for (int i = 0; i < MFR; ++i) {
            int row = wm * (MT / 2) + i * 16 + lrow;
            int s = (g + (row >> 1)) & 3;            // swizzled read slot
            a[i] = *(const short8*)&As[buf][row * 32 + s * 8];
        }
#pragma unroll
        for (int j = 0; j < 4; ++j) {
            int row = wn * 64 + j * 16 + lrow;
            int s = (g + (row >> 1)) & 3;
            b[j] = *(const short8*)&Bs[buf][row * 32 + s * 8];
        }
        asm volatile("s_waitcnt lgkmcnt(0)" ::: "memory");
        __builtin_amdgcn_sched_barrier(0);
        __builtin_amdgcn_s_setprio(1);
#pragma unroll
        for (int i = 0; i < MFR; ++i)
#pragma unroll
            for (int j = 0; j < 4; ++j)
                acc[i][j] = __builtin_amdgcn_mfma_f32_16x16x32_bf16(a[i], b[j], acc[i][j], 0, 0, 0);
        __builtin_amdgcn_s_setprio(0);
    };

    int nk = K >> 5;
    stage(0, 0);
    stage(1, 32);
    for (int t = 0; t < nk - 1; ++t) {
        if constexpr (MT == 128) {
            asm volatile("s_waitcnt vmcnt(4)" ::: "memory");   // tile t landed; t+1 in flight
        } else {
            asm volatile("s_waitcnt vmcnt(3)" ::: "memory");
        }
        __builtin_amdgcn_s_barrier();
        if (t + 2 < nk) stage((t + 2) % 3, (t + 2) << 5);      // overlap with compute below
        do_tile(t % 3);
    }
    asm volatile("s_waitcnt vmcnt(0)" ::: "memory");
    __builtin_amdgcn_s_barrier();
    do_tile((nk - 1) % 3);

    int r0 = g * 4;
#pragma unroll
    for (int i = 0; i < MFR; ++i) {
#pragma unroll
        for (int j = 0; j < 4; ++j) {
            int col = n0 + wn * 64 + j * 16 + lrow;
            if (col >= N) continue;
            float bv = bias ? bias[col] : 0.f;
#pragma unroll
            for (int r = 0; r < 4; ++r) {
                int row = m0 + wm * (MT / 2) + i * 16 + r0 + r;
                float v = acc[i][j][r] + bv;
                if (GELU) {
                    float t = 0.7978845608028654f * (v + 0.044715f * v * v * v);
                    v = 0.5f * v * (1.f + tanhf(t));
                }
                if (RESID) v += resid[(size_t)row * N + col];
                if (QKVPACK) {
                    int bb = row >> 9, tt = row & (T_ - 1);
                    int which = col / 768;
                    int cc = col - which * 768;
                    int hh = cc >> 6, d = cc & 63;
                    size_t bh = (size_t)bb * H_ + hh;
                    unsigned short u = f2bf(v);
                    if (which == 0)      Qp[(bh * T_ + tt) * 64 + d] = u;
                    else if (which == 1) Kp[(bh * T_ + tt) * 64 + d] = u;
                    else                 Vt[(bh * 64 + d) * T_ + tt] = u;
                } else if (OUTBF) {
                    ((unsigned short*)Cout)[(size_t)row * N + col] = f2bf(v);
                } else {
                    ((float*)Cout)[(size_t)row * N + col] = v;
                }
            }
        }
    }
    if (LOSSP) {
#pragma unroll
        for (int i = 0; i < MFR; ++i) {
#pragma unroll
            for (int r = 0; r < 4; ++r) {
                float mx = -1e30f;
#pragma unroll
                for (int j = 0; j < 4; ++j) {
                    int col = n0 + wn * 64 + j * 16 + lrow;
                    if (col < V_) mx = fmaxf(mx, acc[i][j][r]);
                }
#pragma unroll
                for (int d2 = 1; d2 < 16; d2 <<= 1) mx = fmaxf(mx, __shfl_xor(mx, d2, 64));
                float ss = 0.f;
#pragma unroll
                for (int j = 0; j < 4; ++j) {
                    int col = n0 + wn * 64 + j * 16 + lrow;
                    if (col < V_) ss += __expf(acc[i][j][r] - mx);
                }
#pragma unroll
                for (int d2 = 1; d2 < 16; d2 <<= 1) ss += __shfl_xor(ss, d2, 64);
                if ((lane & 15) == 0) {
                    int rloc = wm * (MT / 2) + i * 16 + g * 4 + r;
                    Lm[wn][rloc] = mx;
                    Lsum[wn][rloc] = ss;
                }
            }
        }
        __syncthreads();
        if (tid < MT) {
            float m0v = Lm[0][tid], m1v = Lm[1][tid];
            float mm = fmaxf(m0v, m1v);
            float ss = Lsum[0][tid] * __expf(m0v - mm) + Lsum[1][tid] * __expf(m1v - mm);
            float2 out2; out2.x = mm; out2.y = ss;
            lpart[(size_t)(m0 + tid) * NPAN + npan] = out2;
        }
    }
}

// ---------------- MFMA flash attention: block = (bh, 16-row q-tile), 4 waves split KV ----------
__global__ __launch_bounds__(256) void flash_attn_kernel(
    const unsigned short* __restrict__ Qp, const unsigned short* __restrict__ Kp,
    const unsigned short* __restrict__ Vt, unsigned short* __restrict__ y)
{
    int bid = blockIdx.x;
    int xcd = bid & 7;
    int s_ = bid >> 3;                 // 0..191
    int bh = xcd * 6 + (s_ % 6);       // 6 heads per XCD for KV L2 locality
    int qi = s_ / 6;                   // 0..31
    int b = bh / H_, h = bh % H_;
    int q0 = qi * 16;
    int tid = threadIdx.x;
    int w = tid >> 6;
    int lane = tid & 63;
    int c = lane & 15, g = lane >> 4;

    const unsigned short* Qb = Qp + ((size_t)bh * T_ + q0) * 64;
    const unsigned short* Kb = Kp + (size_t)bh * T_ * 64;
    const unsigned short* Vb = Vt + (size_t)bh * 64 * T_;

    short8 qf0 = *(const short8*)(Qb + (size_t)c * 64 + g * 8);
    short8 qf1 = *(const short8*)(Qb + (size_t)c * 64 + 32 + g * 8);

    f32x4 o[4] = {};
    float mrow[4], lrow[4];
#pragma unroll
    for (int r = 0; r < 4; ++r) { mrow[r] = -1e30f; lrow[r] = 0.f; }

    __shared__ unsigned short P_lds[4][16 * 40];
    __shared__ float oW[4][16][64];
    __shared__ float mW[4][16], lW[4][16];

    int ntiles = q0 / 32 + 1;
    for (int t = w; t < ntiles; t += 4) {
        int kv0 = t * 32;
        f32x4 s[2] = {};
        __builtin_amdgcn_s_setprio(1);
#pragma unroll
        for (int tt = 0; tt < 2; ++tt) {
            const unsigned short* Kt = Kb + (size_t)(kv0 + tt * 16 + c) * 64;
            short8 b0 = *(const short8*)(Kt + g * 8);
            short8 b1 = *(const short8*)(Kt + 32 + g * 8);
            s[tt] = __builtin_amdgcn_mfma_f32_16x16x32_bf16(qf0, b0, s[tt], 0, 0, 0);
            s[tt] = __builtin_amdgcn_mfma_f32_16x16x32_bf16(qf1, b1, s[tt], 0, 0, 0);
        }
        __builtin_amdgcn_s_setprio(0);
        if (kv0 + 32 > q0) {
#pragma unroll
            for (int tt = 0; tt < 2; ++tt)
#pragma unroll
                for (int r = 0; r < 4; ++r) {
                    int kv = kv0 + tt * 16 + c;
                    int qq = q0 + g * 4 + r;
                    float v = s[tt][r] * 0.125f;
                    s[tt][r] = (kv <= qq) ? v : -1e30f;
                }
        } else {
#pragma unroll
            for (int tt = 0; tt < 2; ++tt)
#pragma unroll
                for (int r = 0; r < 4; ++r) s[tt][r] *= 0.125f;
        }
        float pmax[4];
#pragma unroll
        for (int r = 0; r < 4; ++r) pmax[r] = fmaxf(s[0][r], s[1][r]);
#pragma unroll
        for (int d2 = 1; d2 < 16; d2 <<= 1)
#pragma unroll
            for (int r = 0; r < 4; ++r) pmax[r] = fmaxf(pmax[r], __shfl_xor(pmax[r], d2, 64));
        float scl[4], psum[4];
#pragma unroll
        for (int r = 0; r < 4; ++r) {
            float mnew = fmaxf(mrow[r], pmax[r]);
            scl[r] = __expf(mrow[r] - mnew);
            mrow[r] = mnew;
            s[0][r] = __expf(s[0][r] - mnew);
            s[1][r] = __expf(s[1][r] - mnew);
            psum[r] = s[0][r] + s[1][r];
        }
#pragma unroll
        for (int d2 = 1; d2 < 16; d2 <<= 1)
#pragma unroll
            for (int r = 0; r < 4; ++r) psum[r] += __shfl_xor(psum[r], d2, 64);
#pragma unroll
        for (int r = 0; r < 4; ++r) lrow[r] = lrow[r] * scl[r] + psum[r];
#pragma unroll
        for (int j = 0; j < 4; ++j)
#pragma unroll
            for (int r = 0; r < 4; ++r) o[j][r] *= scl[r];
#pragma unroll
        for (int tt = 0; tt < 2; ++tt)
#pragma unroll
            for (int r = 0; r < 4; ++r)
                P_lds[w][(g * 4 + r) * 40 + tt * 16 + c] = f2bf(s[tt][r]);
        asm volatile("s_waitcnt lgkmcnt(0)" ::: "memory");
        __builtin_amdgcn_sched_barrier(0);
        short8 pf = *(const short8*)&P_lds[w][c * 40 + g * 8];
        asm volatile("s_waitcnt lgkmcnt(0)" ::: "memory");
        asm volatile("" ::: "memory");
        __builtin_amdgcn_s_setprio(1);
#pragma unroll
        for (int j = 0; j < 4; ++j) {
            short8 vf = *(const short8*)(Vb + (size_t)(j * 16 + c) * T_ + kv0 + g * 8);
            o[j] = __builtin_amdgcn_mfma_f32_16x16x32_bf16(pf, vf, o[j], 0, 0, 0);
        }
        __builtin_amdgcn_s_setprio(0);
    }
    if (c == 0) {
#pragma unroll
        for (int r = 0; r < 4; ++r) { mW[w][g * 4 + r] = mrow[r]; lW[w][g * 4 + r] = lrow[r]; }
    }
#pragma unroll
    for (int j = 0; j < 4; ++j)
#pragma unroll
        for (int r = 0; r < 4; ++r) oW[w][g * 4 + r][j * 16 + c] = o[j][r];
    __syncthreads();
    unsigned short* yb = y + ((size_t)(b * T_ + q0)) * C_ + h * 64;
    int col = tid & 63;
#pragma unroll
    for (int rr = 0; rr < 4; ++rr) {
        int row = (tid >> 6) * 4 + rr;   // 0..15
        float Mx = fmaxf(fmaxf(mW[0][row], mW[1][row]), fmaxf(mW[2][row], mW[3][row]));
        float Ls = 0.f, Os = 0.f;
#pragma unroll
        for (int ww = 0; ww < 4; ++ww) {
            float e = __expf(mW[ww][row] - Mx);
            Ls += lW[ww][row] * e;
            Os += oW[ww][row][col] * e;
        }
        yb[(size_t)row * C_ + col] = f2bf(Os / Ls);
    }
}

// ---------------- loss reduce over per-panel partials ----------------
__global__ __launch_bounds__(256) void loss_reduce_kernel(
    const float2* __restrict__ lpart, const float* __restrict__ logits,
    const int* __restrict__ targets, float* __restrict__ acc, int NPAN)
{
    int row = blockIdx.x;
    const float2* pp = lpart + (size_t)row * NPAN;
    int tid = threadIdx.x;
    float m = -1e30f, s = 0.f;
    for (int j = tid; j < NPAN; j += 256) {
        float2 p = pp[j];
        float mn = fmaxf(m, p.x);
        s = s * __expf(m - mn) + p.y * __expf(p.x - mn);
        m = mn;
    }
    for (int off = 32; off > 0; off >>= 1) {
        float mo = __shfl_down(m, off, 64);
        float so = __shfl_down(s, off, 64);
        float mn = fmaxf(m, mo);
        s = s * __expf(m - mn) + so * __expf(mo - mn);
        m = mn;
    }
    __shared__ float rm[4], rs[4];
    if ((tid & 63) == 0) { rm[tid >> 6] = m; rs[tid >> 6] = s; }
    __syncthreads();
    if (tid == 0) {
        float M = rm[0], S = rs[0];
        for (int i = 1; i < 4; ++i) {
            float mn = fmaxf(M, rm[i]);
            S = S * __expf(M - mn) + rs[i] * __expf(rm[i] - mn);
            M = mn;
        }
        int t = targets[row];
        if (t != -100) {
            float nll = -(logits[(size_t)row * V_ + t] - M - logf(S));
            atomicAdd(&acc[0], nll);
            atomicAdd(&acc[1], 1.f);
        }
    }
}

__global__ void finalize_loss(const float* __restrict__ acc, float* __restrict__ out)
{
    out[0] = acc[0] / fmaxf(acc[1], 1.f);
}

extern "C" void kernel_launch(void* const* d_in, const int* in_sizes, int n_in,
                              void* d_out, int out_size, void* d_ws, size_t ws_size,
                              hipStream_t stream)
{
    const int*   idx     = (const int*)d_in[0];
    const int*   targets = (const int*)d_in[1];
    const float* wte     = (const float*)d_in[2];
    const float* wpe     = (const float*)d_in[3];
    const float* ln1_w   = (const float*)d_in[4];
    const float* ln1_b   = (const float*)d_in[5];
    const float* attn_w  = (const float*)d_in[6];
    const float* attn_b  = (const float*)d_in[7];
    const float* attnp_w = (const float*)d_in[8];
    const float* attnp_b = (const float*)d_in[9];
    const float* ln2_w   = (const float*)d_in[10];
    const float* ln2_b   = (const float*)d_in[11];
    const float* fc_w    = (const float*)d_in[12];
    const float* fc_b    = (const float*)d_in[13];
    const float* fcp_w   = (const float*)d_in[14];
    const float* fcp_b   = (const float*)d_in[15];
    const float* lnf_w   = (const float*)d_in[16];
    const float* lnf_b   = (const float*)d_in[17];
    const float* lm_w    = (const float*)d_in[18];

    float* logits = (float*)d_out;                    // [M_, V_]
    float* loss   = logits + (size_t)M_ * V_;         // 1 float

    // ---- workspace layout ----
    char* p = (char*)d_ws;
    __hip_bfloat16* aw_t = (__hip_bfloat16*)p; p += (size_t)L_ * 3 * C_ * C_ * 2;
    __hip_bfloat16* pw_t = (__hip_bfloat16*)p; p += (size_t)L_ * C_ * C_ * 2;
    __hip_bfloat16* fw_t = (__hip_bfloat16*)p; p += (size_t)L_ * FF_ * C_ * 2;
    __hip_bfloat16* qw_t = (__hip_bfloat16*)p; p += (size_t)L_ * C_ * FF_ * 2;
    __hip_bfloat16* lm_t = (__hip_bfloat16*)p; p += (size_t)VP_ * C_ * 2;
    float*          x    = (float*)p;          p += (size_t)M_ * C_ * 4;
    __hip_bfloat16* h    = (__hip_bfloat16*)p; p += (size_t)M_ * C_ * 2;
    __hip_bfloat16* y    = (__hip_bfloat16*)p; p += (size_t)M_ * C_ * 2;
    __hip_bfloat16* ff   = (__hip_bfloat16*)p; p += (size_t)M_ * FF_ * 2;
    unsigned short* Qp   = (unsigned short*)p; p += (size_t)BH_ * T_ * 64 * 2;
    unsigned short* Kp   = (unsigned short*)p; p += (size_t)BH_ * T_ * 64 * 2;
    unsigned short* Vt   = (unsigned short*)p; p += (size_t)BH_ * 64 * T_ * 2;
    float2*         lpart= (float2*)p;         p += (size_t)M_ * NPAN_LM * 8;
    float*          acc  = (float*)p;          p += 2 * 4;

    // ---- weight convert+transpose pre-pass ----
    transpose_bf16_kernel<<<dim3(3 * C_ / 64, C_ / 64, L_), 256, 0, stream>>>(attn_w, aw_t, C_, 3 * C_, 3 * C_);
    transpose_bf16_kernel<<<dim3(C_ / 64, C_ / 64, L_), 256, 0, stream>>>(attnp_w, pw_t, C_, C_, C_);
    transpose_bf16_kernel<<<dim3(FF_ / 64, C_ / 64, L_), 256, 0, stream>>>(fc_w, fw_t, C_, FF_, FF_);
    transpose_bf16_kernel<<<dim3(C_ / 64, FF_ / 64, L_), 256, 0, stream>>>(fcp_w, qw_t, FF_, C_, C_);
    transpose_bf16_kernel<<<dim3(VP_ / 64, C_ / 64, 1), 256, 0, stream>>>(lm_w, lm_t, C_, V_, VP_);

    // ---- embedding ----
    {
        int total = M_ * C_;
        embed_kernel<<<(total + 255) / 256, 256, 0, stream>>>(idx, wte, wpe, x, total);
    }

    #define GEMM_GRID(NB, MT) (8 * (((NB) + 7) / 8) * (M_ / (MT)))

    for (int l = 0; l < L_; ++l) {
        const float* l1w = ln1_w + (size_t)l * C_;
        const float* l1b = ln1_b + (size_t)l * C_;
        const __hip_bfloat16* aw = aw_t + (size_t)l * 3 * C_ * C_;
        const float* ab  = attn_b + (size_t)l * 3 * C_;
        const __hip_bfloat16* pw = pw_t + (size_t)l * C_ * C_;
        const float* pb  = attnp_b + (size_t)l * C_;
        const float* l2w = ln2_w + (size_t)l * C_;
        const float* l2b = ln2_b + (size_t)l * C_;
        const __hip_bfloat16* fw = fw_t + (size_t)l * FF_ * C_;
        const float* fb  = fc_b + (size_t)l * FF_;
        const __hip_bfloat16* qw = qw_t + (size_t)l * C_ * FF_;
        const float* qb  = fcp_b + (size_t)l * C_;

        layernorm_kernel<<<M_, 256, 0, stream>>>(x, l1w, l1b, h);
        // qkv GEMM with fused head-pack epilogue
        mfma_gemm<128, 0, 0, 0, 0, 1><<<GEMM_GRID(18, 128), 256, 0, stream>>>(
            h, aw, ab, nullptr, nullptr, M_, 3 * C_, C_, 18, nullptr, 0, Qp, Kp, Vt);
        flash_attn_kernel<<<8 * 6 * 32, 256, 0, stream>>>(Qp, Kp, Vt, (unsigned short*)y);
        mfma_gemm<64, 0, 0, 1, 0, 0><<<GEMM_GRID(6, 64), 256, 0, stream>>>(
            y, pw, pb, x, x, M_, C_, C_, 6, nullptr, 0, nullptr, nullptr, nullptr);
        layernorm_kernel<<<M_, 256, 0, stream>>>(x, l2w, l2b, h);
        mfma_gemm<128, 1, 1, 0, 0, 0><<<GEMM_GRID(24, 128), 256, 0, stream>>>(
            h, fw, fb, nullptr, ff, M_, FF_, C_, 24, nullptr, 0, nullptr, nullptr, nullptr);
        mfma_gemm<64, 0, 0, 1, 0, 0><<<GEMM_GRID(6, 64), 256, 0, stream>>>(
            ff, qw, qb, x, x, M_, C_, FF_, 6, nullptr, 0, nullptr, nullptr, nullptr);
    }

    layernorm_kernel<<<M_, 256, 0, stream>>>(x, lnf_w, lnf_b, h);
    mfma_gemm<128, 0, 0, 0, 1, 0><<<GEMM_GRID(NPAN_LM, 128), 256, 0, stream>>>(
        h, lm_t, nullptr, nullptr, logits, M_, V_, C_, NPAN_LM, lpart, NPAN_LM,
        nullptr, nullptr, nullptr);

    hipMemsetAsync(acc, 0, 2 * sizeof(float), stream);
    loss_reduce_kernel<<<M_, 256, 0, stream>>>(lpart, logits, targets, acc, NPAN_LM);
    finalize_loss<<<1, 1, 0, stream>>>(acc, loss);
}